// Round 11
// baseline (1285.826 us; speedup 1.0000x reference)
//
#include <hip/hip_runtime.h>

#define EPS 1e-5f
#define FIXSCALE 8388608.0f   // 2^23 fixed-point for degree accumulation
#define NB 512                // degree-binning buckets

typedef __attribute__((ext_vector_type(8))) short short8;
typedef __attribute__((ext_vector_type(4))) short short4v;
typedef __attribute__((ext_vector_type(4))) float float4v;
typedef __attribute__((ext_vector_type(2))) float float2v;
typedef __attribute__((ext_vector_type(8))) unsigned short ushort8;
typedef __attribute__((ext_vector_type(4))) unsigned int uint4v;

#if __has_builtin(__builtin_nontemporal_load)
#define NT_LOAD(p) __builtin_nontemporal_load(p)
#else
#define NT_LOAD(p) (*(p))
#endif

__device__ __forceinline__ unsigned short f2b(float f) {
    union { float f; unsigned u; } v; v.f = f;
    unsigned r = v.u + 0x7FFF + ((v.u >> 16) & 1);   // RNE
    return (unsigned short)(r >> 16);
}
__device__ __forceinline__ float b2f(unsigned short u) {
    union { unsigned u; float f; } v; v.u = ((unsigned)u) << 16;
    return v.f;
}

// ---------------- setup kernels ----------------

// ONE atomic per edge; combo padded to 1 node / 64B line
__global__ __launch_bounds__(256) void rank_kernel(const int* __restrict__ dst,
                                                   const float* __restrict__ w,
                                                   unsigned long long* __restrict__ combo,
                                                   int* __restrict__ rank, int E) {
    int e = blockIdx.x * 256 + threadIdx.x;
    if (e < E) {
        int d = dst[e];
        unsigned long long pack = (1ULL << 32) | (unsigned long long)(unsigned)(w[e] * FIXSCALE);
        unsigned long long old = atomicAdd(&combo[(size_t)d * 8], pack);
        rank[e] = (int)(old >> 32);
    }
}

// ---- degree binning: bucket nodes by quad-count so waves get uniform row lengths ----

__global__ __launch_bounds__(256) void bin_hist_kernel(const unsigned long long* __restrict__ combo,
                                                       int* __restrict__ hist, int n) {
    int d = blockIdx.x * 256 + threadIdx.x;
    if (d < n) {
        int cnt = (int)(combo[(size_t)d * 8] >> 32);
        int qc = ((cnt + 4) & ~3) >> 2;
        int b = qc < NB ? qc : NB - 1;
        atomicAdd(&hist[b], 1);
    }
}

// cursor[b] = sum_{b' > b} hist[b']   (descending: big rows first)
__global__ __launch_bounds__(NB) void bucket_scan_kernel(const int* __restrict__ hist,
                                                         int* __restrict__ cursor) {
    __shared__ int v1[NB], v2[NB];
    int t = threadIdx.x;
    v1[t] = hist[t];
    __syncthreads();
    int* cur = v1; int* nxt = v2;
    for (int off = 1; off < NB; off <<= 1) {
        int x = cur[t] + ((t + off < NB) ? cur[t + off] : 0);
        nxt[t] = x;
        __syncthreads();
        int* tmp = cur; cur = nxt; nxt = tmp;
    }
    cursor[t] = cur[t] - hist[t];   // exclusive suffix sum
}

__global__ __launch_bounds__(256) void bin_scatter_kernel(const unsigned long long* __restrict__ combo,
                                                          int* __restrict__ cursor,
                                                          int* __restrict__ perm,
                                                          int* __restrict__ posod, int n) {
    int d = blockIdx.x * 256 + threadIdx.x;
    if (d < n) {
        int cnt = (int)(combo[(size_t)d * 8] >> 32);
        int qc = ((cnt + 4) & ~3) >> 2;
        int b = qc < NB ? qc : NB - 1;
        int pos = atomicAdd(&cursor[b], 1);
        perm[pos] = d;
        posod[d] = pos;
    }
}

// row_ptr over PERMUTED slots (slot i owns node perm[i]); dinv per original node
__global__ __launch_bounds__(1024) void scan_dinv_kernel(const unsigned long long* __restrict__ combo,
                                                         const int* __restrict__ perm,
                                                         int* __restrict__ row_ptr,
                                                         float* __restrict__ dinv, int n) {
    int tid = threadIdx.x, lane = tid & 63, w = tid >> 6;
    __shared__ int wsum[16];
    __shared__ int s_carry;
    if (tid == 0) s_carry = 0;
    __syncthreads();
    for (int base = 0; base < n; base += 1024) {
        int i = base + tid;
        int v = 0;
        if (i < n) {
            unsigned long long cb = combo[(size_t)i * 8];
            float degv = (float)(unsigned)(cb & 0xffffffffULL) * (1.0f / FIXSCALE);
            dinv[i] = rsqrtf(degv + 1.0f);
            int cntp = (int)(combo[(size_t)perm[i] * 8] >> 32);
            v = (cntp + 4) & ~3;
        }
        int x = v;
        for (int off = 1; off < 64; off <<= 1) {
            int t = __shfl_up(x, off);
            if (lane >= off) x += t;
        }
        if (lane == 63) wsum[w] = x;
        __syncthreads();
        if (w == 0 && lane < 16) {
            int s = wsum[lane];
            for (int off = 1; off < 16; off <<= 1) {
                int t = __shfl_up(s, off, 16);
                if (lane >= off) s += t;
            }
            wsum[lane] = s;
        }
        __syncthreads();
        int carry = s_carry;
        int woff = (w > 0) ? wsum[w - 1] : 0;
        if (i < n) row_ptr[i + 1] = carry + woff + x;
        __syncthreads();
        if (tid == 0) s_carry = carry + wsum[15];
        __syncthreads();
    }
    if (tid == 0) row_ptr[0] = 0;
}

// self-edge (slot 0, weight dinv^2) + zero-weight pads, at the node's permuted slot
__global__ __launch_bounds__(256) void selfpad_kernel(const unsigned long long* __restrict__ combo,
                                                      const int* __restrict__ row_ptr,
                                                      const int* __restrict__ posod,
                                                      const float* __restrict__ dinv,
                                                      unsigned int* __restrict__ edge, int n) {
    int d = blockIdx.x * 256 + threadIdx.x;
    if (d < n) {
        int cnt = (int)(combo[(size_t)d * 8] >> 32);
        int slot = posod[d];
        int j0 = row_ptr[slot], j1 = row_ptr[slot + 1];
        float di = dinv[d];
        edge[j0] = ((unsigned)f2b(di * di) << 16) | (unsigned)d;
        for (int j = j0 + 1 + cnt; j < j1; ++j) edge[j] = (unsigned)d;  // w = +0
    }
}

// atomic-free scatter into permuted CSR; record = wn(bf16)<<16 | src(u16)
__global__ __launch_bounds__(256) void scatter2_kernel(
    const int* __restrict__ src, const int* __restrict__ dst,
    const float* __restrict__ w, const int* __restrict__ rank,
    const int* __restrict__ row_ptr, const int* __restrict__ posod,
    const float* __restrict__ dinv, unsigned int* __restrict__ edge, int E) {
    int e = blockIdx.x * 256 + threadIdx.x;
    if (e < E) {
        int d = dst[e], s = src[e];
        float wn = dinv[s] * w[e] * dinv[d];
        edge[row_ptr[posod[d]] + 1 + rank[e]] = ((unsigned)f2b(wn) << 16) | (unsigned)s;
    }
}

// node f32 [N][F] -> bf16 slice-major [F/32][N][32]
__global__ __launch_bounds__(256) void cast_sliced_kernel(const float* __restrict__ in,
                                                          unsigned short* __restrict__ out,
                                                          int n, int F) {
    int idx = blockIdx.x * 256 + threadIdx.x;
    if (idx < n * (F / 4)) {
        int f4 = idx * 4;
        int r = f4 / F, f = f4 - r * F;
        float4 v = *(const float4*)&in[(size_t)r * F + f];
        short4v s = (short4v){(short)f2b(v.x), (short)f2b(v.y), (short)f2b(v.z), (short)f2b(v.w)};
        *(short4v*)&out[((size_t)(f >> 5) * n + r) * 32 + (f & 31)] = s;
    }
}

__global__ __launch_bounds__(256) void wtrans_kernel(const float* __restrict__ W,
                                                     unsigned short* __restrict__ Wt,
                                                     int K, int Nc) {
    int o = blockIdx.x * 256 + threadIdx.x;
    if (o < K * Nc) {
        int n = o / K, k = o - n * K;
        Wt[o] = f2b(W[(size_t)k * Nc + n]);
    }
}

// ---------------- bf16 MFMA GEMM, full-N strip: C[M,256] = A[M,K](bf16) @ Bt[256,K]^T ----

#define GST 88

template <bool SLICEOUT>
__global__ __launch_bounds__(256) void gemm_n256(const unsigned short* __restrict__ A,
                                                 const unsigned short* __restrict__ Bt,
                                                 unsigned short* __restrict__ Cout,
                                                 const float* __restrict__ bias,
                                                 int M, int K) {
    __shared__ __align__(16) short As[64 * GST];
    __shared__ __align__(16) short Bs[256 * GST];
    int t = threadIdx.x;
    int lane = t & 63, w = t >> 6;
    int quad = lane >> 4, l16 = lane & 15;
    int row0 = blockIdx.x * 64;

    float4v acc[16];
#pragma unroll
    for (int c = 0; c < 16; ++c) acc[c] = (float4v){0.f, 0.f, 0.f, 0.f};

    int arow = t >> 2, ak16 = (t & 3) * 16;
    int bcol0 = t >> 2, bko = (t & 3) * 16;

    for (int k_outer = 0; k_outer < K; k_outer += 64) {
        bool rowok = (row0 + arow) < M;
        const unsigned short* ap = &A[(size_t)(row0 + arow) * K + k_outer + ak16];
        uint4 z = make_uint4(0, 0, 0, 0);
        uint4 u0 = rowok ? *(const uint4*)ap : z;
        uint4 u1 = rowok ? *(const uint4*)(ap + 8) : z;
        *(uint4*)&As[arow * GST + ak16] = u0;
        *(uint4*)&As[arow * GST + ak16 + 8] = u1;
#pragma unroll
        for (int cb = 0; cb < 4; ++cb) {
            int col = bcol0 + 64 * cb;
            const unsigned short* bp = &Bt[(size_t)col * K + k_outer + bko];
#pragma unroll
            for (int u = 0; u < 2; ++u)
                *(uint4*)&Bs[col * GST + bko + u * 8] = *(const uint4*)&bp[u * 8];
        }
        __syncthreads();
#pragma unroll
        for (int k0 = 0; k0 < 64; k0 += 32) {
            short8 a = *(const short8*)&As[(w * 16 + l16) * GST + k0 + quad * 8];
#pragma unroll
            for (int c = 0; c < 16; ++c) {
                short8 b = *(const short8*)&Bs[(c * 16 + l16) * GST + k0 + quad * 8];
                acc[c] = __builtin_amdgcn_mfma_f32_16x16x32_bf16(a, b, acc[c], 0, 0, 0);
            }
        }
        __syncthreads();
    }
#pragma unroll
    for (int c = 0; c < 16; ++c) {
        int col = c * 16 + l16;
        float bcol = (!SLICEOUT) ? bias[col] : 0.0f;
#pragma unroll
        for (int r = 0; r < 4; ++r) {
            int row = row0 + w * 16 + quad * 4 + r;
            if (row < M) {
                if (SLICEOUT)
                    Cout[((size_t)(c >> 1) * M + row) * 32 + ((c & 1) << 4) + l16] = f2b(acc[c][r]);
                else
                    Cout[(size_t)row * 256 + col] = f2b(acc[c][r] + bcol);
            }
        }
    }
}

// ---------------- aggregation: 4-lane group per PERMUTED slot, slice-major table --------
// Slots are degree-binned -> the 16 groups of a wave have near-equal row lengths (no
// exec-divergence waste). LDS edge staging (16 KB), slice = blockIdx & mask -> XCD-
// resident 3.2MB slice. float2-packed MAC (v_pk_fma_f32). Output row = perm[slot].

#define CAPQ 1024   // 4096 edges, 16 KB LDS

template <int CSH>
__global__ __launch_bounds__(256) void agg_grp(
    const unsigned short* __restrict__ tab0, const int* __restrict__ row_ptr,
    const int* __restrict__ perm, const unsigned int* __restrict__ edge,
    unsigned short* __restrict__ outb, int n) {
    __shared__ uint4v eq[CAPQ];
    int b = blockIdx.x;
    int s = b & ((1 << CSH) - 1);
    int grp = b >> CSH;
    int t = threadIdx.x;
    int d0 = grp * 64;
    int d = d0 + (t >> 2);

    const uint4v* e4p = (const uint4v*)edge;
    int qbase = row_ptr[d0] >> 2;
    int dmax = d0 + 64 < n ? d0 + 64 : n;
    int qcnt = (row_ptr[dmax] >> 2) - qbase;
    int qstage = qcnt < CAPQ ? qcnt : CAPQ;
    for (int i = t; i < qstage; i += 256) eq[i] = NT_LOAD(&e4p[qbase + i]);
    __syncthreads();

    if (d >= n) return;
    int fo = (t & 3) << 3;                    // feature offset within the 32-wide slice
    const unsigned short* tab = tab0 + (size_t)s * n * 32;

    int j = row_ptr[d] >> 2, j1 = row_ptr[d + 1] >> 2;
    int jmid = j1 < qbase + CAPQ ? j1 : qbase + CAPQ;

    float2v a2[4];
#pragma unroll
    for (int k = 0; k < 4; ++k) a2[k] = (float2v){0.f, 0.f};

    auto process = [&](uint4v e4) {
#pragma unroll
        for (int u = 0; u < 4; ++u) {
            unsigned e = e4[u];
            float wq = __int_as_float((int)(e & 0xffff0000u));
            float2v w2 = {wq, wq};
            unsigned off = ((e & 0xffffu) << 5) + (unsigned)fo;
            uint4 rr = *(const uint4*)(tab + off);
            unsigned uu0 = rr.x, uu1 = rr.y, uu2 = rr.z, uu3 = rr.w;
            float2v f0 = {__uint_as_float(uu0 << 16), __uint_as_float(uu0 & 0xffff0000u)};
            float2v f1 = {__uint_as_float(uu1 << 16), __uint_as_float(uu1 & 0xffff0000u)};
            float2v f2 = {__uint_as_float(uu2 << 16), __uint_as_float(uu2 & 0xffff0000u)};
            float2v f3 = {__uint_as_float(uu3 << 16), __uint_as_float(uu3 & 0xffff0000u)};
            a2[0] += f0 * w2;
            a2[1] += f1 * w2;
            a2[2] += f2 * w2;
            a2[3] += f3 * w2;
        }
    };

    for (; j + 2 <= jmid; j += 2) {
        uint4v e4a = eq[j - qbase];
        uint4v e4b = eq[j + 1 - qbase];
        process(e4a);
        process(e4b);
    }
    if (j < jmid) { process(eq[j - qbase]); ++j; }
    for (; j < j1; ++j) process(NT_LOAD(&e4p[j]));   // overflow fallback (rare)

    int p = perm[d];
    ushort8 o;
#pragma unroll
    for (int k = 0; k < 4; ++k) {
        o[2 * k] = f2b(a2[k].x);
        o[2 * k + 1] = f2b(a2[k].y);
    }
    *(ushort8*)(outb + ((size_t)p << (5 + CSH)) + (s << 5) + fo) = o;
}

// ---------------- bias + LayerNorm + residual + ReLU (bf16 in, bf16 out) ----------------

__global__ __launch_bounds__(256) void ln_res_relu(
    const unsigned short* __restrict__ preln, const float* __restrict__ bias,
    const float* __restrict__ g, const float* __restrict__ lb,
    const unsigned short* __restrict__ res, unsigned short* __restrict__ out, int n) {
    int wv = __builtin_amdgcn_readfirstlane(threadIdx.x >> 6);
    int d = blockIdx.x * 4 + wv;
    if (d >= n) return;
    int l = threadIdx.x & 63;
    int fo = l * 4;
    ushort4 pv = *(const ushort4*)&preln[(size_t)d * 256 + fo];
    float4 bb = *(const float4*)&bias[fo];
    float v[4] = {b2f(pv.x) + bb.x, b2f(pv.y) + bb.y, b2f(pv.z) + bb.z, b2f(pv.w) + bb.w};
    float s4 = v[0] + v[1] + v[2] + v[3];
#pragma unroll
    for (int off = 1; off < 64; off <<= 1) s4 += __shfl_xor(s4, off);
    float mu = s4 * (1.0f / 256.0f);
    float dv[4];
    float qs = 0.f;
#pragma unroll
    for (int j = 0; j < 4; ++j) { dv[j] = v[j] - mu; qs += dv[j] * dv[j]; }
#pragma unroll
    for (int off = 1; off < 64; off <<= 1) qs += __shfl_xor(qs, off);
    float rs = rsqrtf(qs * (1.0f / 256.0f) + EPS);

    float4 gg = *(const float4*)&g[fo];
    float4 lbv = *(const float4*)&lb[fo];
    ushort4 rr4 = *(const ushort4*)&res[(size_t)d * 256 + fo];
    float ggv[4] = {gg.x, gg.y, gg.z, gg.w};
    float lbvv[4] = {lbv.x, lbv.y, lbv.z, lbv.w};
    float rrv[4] = {b2f(rr4.x), b2f(rr4.y), b2f(rr4.z), b2f(rr4.w)};
    ushort4 o;
    unsigned short* op = (unsigned short*)&o;
#pragma unroll
    for (int j = 0; j < 4; ++j) {
        float x = dv[j] * rs * ggv[j] + lbvv[j] + rrv[j];
        op[j] = f2b(x > 0.f ? x : 0.f);
    }
    *(ushort4*)&out[(size_t)d * 256 + fo] = o;
}

// ---------------- head ----------------

__global__ __launch_bounds__(256) void colsum_kernel(const unsigned short* __restrict__ x,
                                                     float* __restrict__ sums, int n) {
    int h = threadIdx.x;
    float acc = 0.0f;
    for (int r = blockIdx.x; r < n; r += gridDim.x) acc += b2f(x[(size_t)r * 256 + h]);
    atomicAdd(&sums[h], acc);
}

__global__ __launch_bounds__(64) void final_kernel(const float* __restrict__ sums,
                                                   const float* __restrict__ fcW,
                                                   const float* __restrict__ fcb,
                                                   float* __restrict__ out, float invN) {
    int lane = threadIdx.x;
    float p0 = 0.0f, p1 = 0.0f;
    for (int hh = lane; hh < 256; hh += 64) {
        float m = sums[hh];
        p0 += m * fcW[hh * 2 + 0];
        p1 += m * fcW[hh * 2 + 1];
    }
    for (int off = 32; off > 0; off >>= 1) {
        p0 += __shfl_down(p0, off);
        p1 += __shfl_down(p1, off);
    }
    if (lane == 0) {
        out[0] = p0 * invN + fcb[0];
        out[1] = p1 * invN + fcb[1];
    }
}

// ---------------- launch ----------------

extern "C" void kernel_launch(void* const* d_in, const int* in_sizes, int n_in,
                              void* d_out, int out_size, void* d_ws, size_t ws_size,
                              hipStream_t stream) {
    const float* node    = (const float*)d_in[0];
    const int*   edges   = (const int*)d_in[1];
    const float* eattr   = (const float*)d_in[2];
    const float* W1      = (const float*)d_in[3];
    const float* b1      = (const float*)d_in[4];
    const float* W_convs = (const float*)d_in[5];
    const float* b_convs = (const float*)d_in[6];
    const float* ln_g    = (const float*)d_in[7];
    const float* ln_b    = (const float*)d_in[8];
    const float* fc_W    = (const float*)d_in[9];
    const float* fc_b    = (const float*)d_in[10];
    float* out = (float*)d_out;

    const int H = in_sizes[4];           // 256
    const int F = in_sizes[3] / H;       // 128
    const int N = in_sizes[0] / F;       // 50000
    const int E = in_sizes[2];           // 1600000
    const int L = in_sizes[6] / H;       // 3

    const int* src = edges;
    const int* dst = edges + E;

    char* p = (char*)d_ws;
    auto alloc = [&](size_t bytes) {
        char* r = p;
        p += (bytes + 255) & ~(size_t)255;
        return r;
    };
    // zeroed region: padded combo (64B/node) + colsums + hist, contiguous
    unsigned long long* combo = (unsigned long long*)alloc((size_t)N * 64);
    float* colsums = (float*)alloc((size_t)H * 4);
    int*   hist    = (int*)alloc((size_t)NB * 4);
    size_t zero_bytes = (size_t)((char*)hist - (char*)combo) + (((size_t)NB * 4 + 255) & ~(size_t)255);
    int*   cursor  = (int*)alloc((size_t)NB * 4);
    int*   perm    = (int*)alloc((size_t)N * 4);
    int*   posod   = (int*)alloc((size_t)N * 4);
    float* dinv    = (float*)alloc((size_t)N * 4);
    int*   row_ptr = (int*)alloc((size_t)(N + 1) * 4);
    unsigned int* edge = (unsigned int*)alloc(((size_t)E + 4 * (size_t)N + 64) * 4);
    unsigned short* Wt1 = (unsigned short*)alloc((size_t)H * F * 2);
    unsigned short* Wtc = (unsigned short*)alloc((size_t)L * H * H * 2);
    unsigned short* xw  = (unsigned short*)alloc((size_t)N * H * 2);   // sliced [8][N][32]
    unsigned short* preln = (unsigned short*)alloc((size_t)N * H * 2); // row-major [N][256]
    unsigned short* bufA  = (unsigned short*)alloc((size_t)N * H * 2); // bf16 x
    unsigned short* bufB  = (unsigned short*)alloc((size_t)N * H * 2); // bf16 x
    // aliases (dead before their slabs' first real use):
    int*            rank  = (int*)xw;                     // E*4 <= N*H*2
    unsigned short* nodeb = preln;                        // sliced [4][N][32] = N*128 shorts
    unsigned short* aggn  = preln + (size_t)N * F;        // bf16 [N][128] row-major

    hipMemsetAsync(combo, 0, zero_bytes, stream);

    int gE = (E + 255) / 256;
    int gN = (N + 255) / 256;
    rank_kernel<<<gE, 256, 0, stream>>>(dst, eattr, combo, rank, E);
    bin_hist_kernel<<<gN, 256, 0, stream>>>(combo, hist, N);
    bucket_scan_kernel<<<1, NB, 0, stream>>>(hist, cursor);
    bin_scatter_kernel<<<gN, 256, 0, stream>>>(combo, cursor, perm, posod, N);
    scan_dinv_kernel<<<1, 1024, 0, stream>>>(combo, perm, row_ptr, dinv, N);
    selfpad_kernel<<<gN, 256, 0, stream>>>(combo, row_ptr, posod, dinv, edge, N);
    scatter2_kernel<<<gE, 256, 0, stream>>>(src, dst, eattr, rank, row_ptr, posod, dinv, edge, E);

    cast_sliced_kernel<<<(N * (F / 4) + 255) / 256, 256, 0, stream>>>(node, nodeb, N, F);
    wtrans_kernel<<<(F * H + 255) / 256, 256, 0, stream>>>(W1, Wt1, F, H);
    for (int i = 0; i < L; ++i)
        wtrans_kernel<<<(H * H + 255) / 256, 256, 0, stream>>>(
            W_convs + (size_t)i * H * H, Wtc + (size_t)i * H * H, H, H);

    int ngrp64 = (N + 63) / 64;
    int lngrid = (N + 3) / 4;
    int ggrid = (N + 63) / 64;

    // layer 1: aggn = agg(node) [bf16 row-major]; x1 = aggn @ W1 + b1 (bf16)
    agg_grp<2><<<4 * ngrp64, 256, 0, stream>>>(nodeb, row_ptr, perm, edge, aggn, N);
    gemm_n256<false><<<ggrid, 256, 0, stream>>>(aggn, Wt1, bufA, b1, N, F);

    unsigned short* x = bufA;
    unsigned short* other = bufB;
    for (int i = 0; i < L; ++i) {
        gemm_n256<true><<<ggrid, 256, 0, stream>>>(x, Wtc + (size_t)i * H * H, xw, nullptr, N, H);
        agg_grp<3><<<8 * ngrp64, 256, 0, stream>>>(xw, row_ptr, perm, edge, preln, N);
        ln_res_relu<<<lngrid, 256, 0, stream>>>(preln, b_convs + (size_t)i * H,
                                                ln_g + (size_t)i * H, ln_b + (size_t)i * H,
                                                x, other, N);
        unsigned short* t = x; x = other; other = t;
    }

    colsum_kernel<<<256, 256, 0, stream>>>(x, colsums, N);
    final_kernel<<<1, 64, 0, stream>>>(colsums, fc_W, fc_b, out, 1.0f / (float)N);
}

// Round 12
// 1193.861 us; speedup vs baseline: 1.0770x; 1.0770x over previous
//
#include <hip/hip_runtime.h>

#define EPS 1e-5f
#define FIXSCALE 8388608.0f   // 2^23 fixed-point for degree accumulation
#define NBK 64                // degree buckets (qc clamped)

typedef __attribute__((ext_vector_type(8))) short short8;
typedef __attribute__((ext_vector_type(4))) short short4v;
typedef __attribute__((ext_vector_type(4))) float float4v;
typedef __attribute__((ext_vector_type(2))) float float2v;
typedef __attribute__((ext_vector_type(8))) unsigned short ushort8;
typedef __attribute__((ext_vector_type(4))) unsigned int uint4v;

#if __has_builtin(__builtin_nontemporal_load)
#define NT_LOAD(p) __builtin_nontemporal_load(p)
#else
#define NT_LOAD(p) (*(p))
#endif

__device__ __forceinline__ unsigned short f2b(float f) {
    union { float f; unsigned u; } v; v.f = f;
    unsigned r = v.u + 0x7FFF + ((v.u >> 16) & 1);   // RNE
    return (unsigned short)(r >> 16);
}
__device__ __forceinline__ float b2f(unsigned short u) {
    union { unsigned u; float f; } v; v.u = ((unsigned)u) << 16;
    return v.f;
}

__device__ __forceinline__ int qbucket(int cnt) {
    int qc = ((cnt + 4) & ~3) >> 2;
    return qc < NBK - 1 ? qc : NBK - 1;
}

// ---------------- setup kernels ----------------

// ONE atomic per edge; combo padded to 1 node / 64B line
__global__ __launch_bounds__(256) void rank_kernel(const int* __restrict__ dst,
                                                   const float* __restrict__ w,
                                                   unsigned long long* __restrict__ combo,
                                                   int* __restrict__ rank, int E) {
    int e = blockIdx.x * 256 + threadIdx.x;
    if (e < E) {
        int d = dst[e];
        unsigned long long pack = (1ULL << 32) | (unsigned long long)(unsigned)(w[e] * FIXSCALE);
        unsigned long long old = atomicAdd(&combo[(size_t)d * 8], pack);
        rank[e] = (int)(old >> 32);
    }
}

// ---- contention-free counting sort by row quad-count (descending) ----

// per-block LDS histogram -> blockhist; LDS atomics only
__global__ __launch_bounds__(256) void bin_hist_kernel(const unsigned long long* __restrict__ combo,
                                                       int* __restrict__ blockhist, int n) {
    __shared__ int lh[NBK];
    int t = threadIdx.x;
    if (t < NBK) lh[t] = 0;
    __syncthreads();
    int d = blockIdx.x * 256 + t;
    if (d < n) {
        int cnt = (int)(combo[(size_t)d * 8] >> 32);
        atomicAdd(&lh[qbucket(cnt)], 1);
    }
    __syncthreads();
    if (t < NBK) blockhist[blockIdx.x * NBK + t] = lh[t];
}

// bucket bases (descending qc) + per-(block,bucket) bases; 64 threads
__global__ __launch_bounds__(NBK) void bin_offsets_kernel(const int* __restrict__ blockhist,
                                                          int* __restrict__ blockbase, int nblk) {
    __shared__ int base[NBK];
    int t = threadIdx.x;
    if (t == 0) {
        int tot[NBK];
        for (int b = 0; b < NBK; ++b) {
            int s = 0;
            for (int blk = 0; blk < nblk; ++blk) s += blockhist[blk * NBK + b];
            tot[b] = s;
        }
        int acc = 0;
        for (int b = NBK - 1; b >= 0; --b) { base[b] = acc; acc += tot[b]; }
    }
    __syncthreads();
    int off = base[t];
    for (int blk = 0; blk < nblk; ++blk) {
        blockbase[blk * NBK + t] = off;
        off += blockhist[blk * NBK + t];
    }
}

// assign slots via LDS cursors (no global atomics)
__global__ __launch_bounds__(256) void bin_scatter_kernel(const unsigned long long* __restrict__ combo,
                                                          const int* __restrict__ blockbase,
                                                          int* __restrict__ perm,
                                                          int* __restrict__ posod, int n) {
    __shared__ int lcur[NBK];
    int t = threadIdx.x;
    if (t < NBK) lcur[t] = blockbase[blockIdx.x * NBK + t];
    __syncthreads();
    int d = blockIdx.x * 256 + t;
    if (d < n) {
        int cnt = (int)(combo[(size_t)d * 8] >> 32);
        int pos = atomicAdd(&lcur[qbucket(cnt)], 1);
        perm[pos] = d;
        posod[d] = pos;
    }
}

// row_ptr over permuted slots; dinv per original node
__global__ __launch_bounds__(1024) void scan_dinv_kernel(const unsigned long long* __restrict__ combo,
                                                         const int* __restrict__ perm,
                                                         int* __restrict__ row_ptr,
                                                         float* __restrict__ dinv, int n) {
    int tid = threadIdx.x, lane = tid & 63, w = tid >> 6;
    __shared__ int wsum[16];
    __shared__ int s_carry;
    if (tid == 0) s_carry = 0;
    __syncthreads();
    for (int base = 0; base < n; base += 1024) {
        int i = base + tid;
        int v = 0;
        if (i < n) {
            unsigned long long cb = combo[(size_t)i * 8];
            float degv = (float)(unsigned)(cb & 0xffffffffULL) * (1.0f / FIXSCALE);
            dinv[i] = rsqrtf(degv + 1.0f);
            int cntp = (int)(combo[(size_t)perm[i] * 8] >> 32);
            v = (cntp + 4) & ~3;
        }
        int x = v;
        for (int off = 1; off < 64; off <<= 1) {
            int t = __shfl_up(x, off);
            if (lane >= off) x += t;
        }
        if (lane == 63) wsum[w] = x;
        __syncthreads();
        if (w == 0 && lane < 16) {
            int s = wsum[lane];
            for (int off = 1; off < 16; off <<= 1) {
                int t = __shfl_up(s, off, 16);
                if (lane >= off) s += t;
            }
            wsum[lane] = s;
        }
        __syncthreads();
        int carry = s_carry;
        int woff = (w > 0) ? wsum[w - 1] : 0;
        if (i < n) row_ptr[i + 1] = carry + woff + x;
        __syncthreads();
        if (tid == 0) s_carry = carry + wsum[15];
        __syncthreads();
    }
    if (tid == 0) row_ptr[0] = 0;
}

// self-edge (slot 0, weight dinv^2, src = own slot) + zero-weight pads
__global__ __launch_bounds__(256) void selfpad_kernel(const unsigned long long* __restrict__ combo,
                                                      const int* __restrict__ row_ptr,
                                                      const int* __restrict__ posod,
                                                      const float* __restrict__ dinv,
                                                      unsigned int* __restrict__ edge, int n) {
    int d = blockIdx.x * 256 + threadIdx.x;
    if (d < n) {
        int cnt = (int)(combo[(size_t)d * 8] >> 32);
        int slot = posod[d];
        int j0 = row_ptr[slot], j1 = row_ptr[slot + 1];
        float di = dinv[d];
        edge[j0] = ((unsigned)f2b(di * di) << 16) | (unsigned)slot;
        for (int j = j0 + 1 + cnt; j < j1; ++j) edge[j] = (unsigned)slot;  // w = +0
    }
}

// atomic-free scatter into permuted CSR; record = wn(bf16)<<16 | srcslot(u16)
__global__ __launch_bounds__(256) void scatter2_kernel(
    const int* __restrict__ src, const int* __restrict__ dst,
    const float* __restrict__ w, const int* __restrict__ rank,
    const int* __restrict__ row_ptr, const int* __restrict__ posod,
    const float* __restrict__ dinv, unsigned int* __restrict__ edge, int E) {
    int e = blockIdx.x * 256 + threadIdx.x;
    if (e < E) {
        int d = dst[e], s = src[e];
        float wn = dinv[s] * w[e] * dinv[d];
        edge[row_ptr[posod[d]] + 1 + rank[e]] = ((unsigned)f2b(wn) << 16) | (unsigned)posod[s];
    }
}

// node f32 [N][F] (original order) -> bf16 slice-major [F/32][n][32] in SLOT order
__global__ __launch_bounds__(256) void cast_sliced_kernel(const float* __restrict__ in,
                                                          const int* __restrict__ perm,
                                                          unsigned short* __restrict__ out,
                                                          int n, int F) {
    int idx = blockIdx.x * 256 + threadIdx.x;
    if (idx < n * (F / 4)) {
        int f4 = idx * 4;
        int slot = f4 / F, f = f4 - slot * F;
        float4 v = *(const float4*)&in[(size_t)perm[slot] * F + f];
        short4v s = (short4v){(short)f2b(v.x), (short)f2b(v.y), (short)f2b(v.z), (short)f2b(v.w)};
        *(short4v*)&out[((size_t)(f >> 5) * n + slot) * 32 + (f & 31)] = s;
    }
}

__global__ __launch_bounds__(256) void wtrans_kernel(const float* __restrict__ W,
                                                     unsigned short* __restrict__ Wt,
                                                     int K, int Nc) {
    int o = blockIdx.x * 256 + threadIdx.x;
    if (o < K * Nc) {
        int n = o / K, k = o - n * K;
        Wt[o] = f2b(W[(size_t)k * Nc + n]);
    }
}

// ---------------- bf16 MFMA GEMM, full-N strip: C[M,256] = A[M,K](bf16) @ Bt[256,K]^T ----

#define GST 88

template <bool SLICEOUT>
__global__ __launch_bounds__(256) void gemm_n256(const unsigned short* __restrict__ A,
                                                 const unsigned short* __restrict__ Bt,
                                                 unsigned short* __restrict__ Cout,
                                                 const float* __restrict__ bias,
                                                 int M, int K) {
    __shared__ __align__(16) short As[64 * GST];
    __shared__ __align__(16) short Bs[256 * GST];
    int t = threadIdx.x;
    int lane = t & 63, w = t >> 6;
    int quad = lane >> 4, l16 = lane & 15;
    int row0 = blockIdx.x * 64;

    float4v acc[16];
#pragma unroll
    for (int c = 0; c < 16; ++c) acc[c] = (float4v){0.f, 0.f, 0.f, 0.f};

    int arow = t >> 2, ak16 = (t & 3) * 16;
    int bcol0 = t >> 2, bko = (t & 3) * 16;

    for (int k_outer = 0; k_outer < K; k_outer += 64) {
        bool rowok = (row0 + arow) < M;
        const unsigned short* ap = &A[(size_t)(row0 + arow) * K + k_outer + ak16];
        uint4 z = make_uint4(0, 0, 0, 0);
        uint4 u0 = rowok ? *(const uint4*)ap : z;
        uint4 u1 = rowok ? *(const uint4*)(ap + 8) : z;
        *(uint4*)&As[arow * GST + ak16] = u0;
        *(uint4*)&As[arow * GST + ak16 + 8] = u1;
#pragma unroll
        for (int cb = 0; cb < 4; ++cb) {
            int col = bcol0 + 64 * cb;
            const unsigned short* bp = &Bt[(size_t)col * K + k_outer + bko];
#pragma unroll
            for (int u = 0; u < 2; ++u)
                *(uint4*)&Bs[col * GST + bko + u * 8] = *(const uint4*)&bp[u * 8];
        }
        __syncthreads();
#pragma unroll
        for (int k0 = 0; k0 < 64; k0 += 32) {
            short8 a = *(const short8*)&As[(w * 16 + l16) * GST + k0 + quad * 8];
#pragma unroll
            for (int c = 0; c < 16; ++c) {
                short8 b = *(const short8*)&Bs[(c * 16 + l16) * GST + k0 + quad * 8];
                acc[c] = __builtin_amdgcn_mfma_f32_16x16x32_bf16(a, b, acc[c], 0, 0, 0);
            }
        }
        __syncthreads();
    }
#pragma unroll
    for (int c = 0; c < 16; ++c) {
        int col = c * 16 + l16;
        float bcol = (!SLICEOUT) ? bias[col] : 0.0f;
#pragma unroll
        for (int r = 0; r < 4; ++r) {
            int row = row0 + w * 16 + quad * 4 + r;
            if (row < M) {
                if (SLICEOUT)
                    Cout[((size_t)(c >> 1) * M + row) * 32 + ((c & 1) << 4) + l16] = f2b(acc[c][r]);
                else
                    Cout[(size_t)row * 256 + col] = f2b(acc[c][r] + bcol);
            }
        }
    }
}

// ---------------- aggregation: 4-lane group per slot, slice-major table, LDS edges ------
// Slots are degree-sorted (descending) -> all 16 groups of a wave have near-equal row
// lengths: no exec-divergence. Everything (table rows, edge src ids, output rows) is in
// slot space. slice = blockIdx & mask -> XCD-resident 3.2MB slice. 16 KB LDS edge stage.

#define CAPQ 1024   // 4096 edges, 16 KB LDS

template <int CSH>
__global__ __launch_bounds__(256) void agg_grp(
    const unsigned short* __restrict__ tab0, const int* __restrict__ row_ptr,
    const unsigned int* __restrict__ edge, unsigned short* __restrict__ outb, int n) {
    __shared__ uint4v eq[CAPQ];
    int b = blockIdx.x;
    int s = b & ((1 << CSH) - 1);
    int grp = b >> CSH;
    int t = threadIdx.x;
    int d0 = grp * 64;
    int d = d0 + (t >> 2);

    const uint4v* e4p = (const uint4v*)edge;
    int qbase = row_ptr[d0] >> 2;
    int dmax = d0 + 64 < n ? d0 + 64 : n;
    int qcnt = (row_ptr[dmax] >> 2) - qbase;
    int qstage = qcnt < CAPQ ? qcnt : CAPQ;
    for (int i = t; i < qstage; i += 256) eq[i] = NT_LOAD(&e4p[qbase + i]);
    __syncthreads();

    if (d >= n) return;
    int fo = (t & 3) << 3;                    // feature offset within the 32-wide slice
    const unsigned short* tab = tab0 + (size_t)s * n * 32;

    int j = row_ptr[d] >> 2, j1 = row_ptr[d + 1] >> 2;
    int jmid = j1 < qbase + CAPQ ? j1 : qbase + CAPQ;

    float2v a2[4];
#pragma unroll
    for (int k = 0; k < 4; ++k) a2[k] = (float2v){0.f, 0.f};

    auto process = [&](uint4v e4) {
#pragma unroll
        for (int u = 0; u < 4; ++u) {
            unsigned e = e4[u];
            float wq = __int_as_float((int)(e & 0xffff0000u));
            float2v w2 = {wq, wq};
            unsigned off = ((e & 0xffffu) << 5) + (unsigned)fo;
            uint4 rr = *(const uint4*)(tab + off);
            unsigned uu0 = rr.x, uu1 = rr.y, uu2 = rr.z, uu3 = rr.w;
            float2v f0 = {__uint_as_float(uu0 << 16), __uint_as_float(uu0 & 0xffff0000u)};
            float2v f1 = {__uint_as_float(uu1 << 16), __uint_as_float(uu1 & 0xffff0000u)};
            float2v f2 = {__uint_as_float(uu2 << 16), __uint_as_float(uu2 & 0xffff0000u)};
            float2v f3 = {__uint_as_float(uu3 << 16), __uint_as_float(uu3 & 0xffff0000u)};
            a2[0] += f0 * w2;
            a2[1] += f1 * w2;
            a2[2] += f2 * w2;
            a2[3] += f3 * w2;
        }
    };

    for (; j + 2 <= jmid; j += 2) {
        uint4v e4a = eq[j - qbase];
        uint4v e4b = eq[j + 1 - qbase];
        process(e4a);
        process(e4b);
    }
    if (j < jmid) { process(eq[j - qbase]); ++j; }
    for (; j < j1; ++j) process(NT_LOAD(&e4p[j]));   // overflow fallback (first blocks only)

    ushort8 o;
#pragma unroll
    for (int k = 0; k < 4; ++k) {
        o[2 * k] = f2b(a2[k].x);
        o[2 * k + 1] = f2b(a2[k].y);
    }
    *(ushort8*)(outb + ((size_t)d << (5 + CSH)) + (s << 5) + fo) = o;
}

// ---------------- bias + LayerNorm + residual + ReLU (bf16 in, bf16 out) ----------------

__global__ __launch_bounds__(256) void ln_res_relu(
    const unsigned short* __restrict__ preln, const float* __restrict__ bias,
    const float* __restrict__ g, const float* __restrict__ lb,
    const unsigned short* __restrict__ res, unsigned short* __restrict__ out, int n) {
    int wv = __builtin_amdgcn_readfirstlane(threadIdx.x >> 6);
    int d = blockIdx.x * 4 + wv;
    if (d >= n) return;
    int l = threadIdx.x & 63;
    int fo = l * 4;
    ushort4 pv = *(const ushort4*)&preln[(size_t)d * 256 + fo];
    float4 bb = *(const float4*)&bias[fo];
    float v[4] = {b2f(pv.x) + bb.x, b2f(pv.y) + bb.y, b2f(pv.z) + bb.z, b2f(pv.w) + bb.w};
    float s4 = v[0] + v[1] + v[2] + v[3];
#pragma unroll
    for (int off = 1; off < 64; off <<= 1) s4 += __shfl_xor(s4, off);
    float mu = s4 * (1.0f / 256.0f);
    float dv[4];
    float qs = 0.f;
#pragma unroll
    for (int j = 0; j < 4; ++j) { dv[j] = v[j] - mu; qs += dv[j] * dv[j]; }
#pragma unroll
    for (int off = 1; off < 64; off <<= 1) qs += __shfl_xor(qs, off);
    float rs = rsqrtf(qs * (1.0f / 256.0f) + EPS);

    float4 gg = *(const float4*)&g[fo];
    float4 lbv = *(const float4*)&lb[fo];
    ushort4 rr4 = *(const ushort4*)&res[(size_t)d * 256 + fo];
    float ggv[4] = {gg.x, gg.y, gg.z, gg.w};
    float lbvv[4] = {lbv.x, lbv.y, lbv.z, lbv.w};
    float rrv[4] = {b2f(rr4.x), b2f(rr4.y), b2f(rr4.z), b2f(rr4.w)};
    ushort4 o;
    unsigned short* op = (unsigned short*)&o;
#pragma unroll
    for (int j = 0; j < 4; ++j) {
        float x = dv[j] * rs * ggv[j] + lbvv[j] + rrv[j];
        op[j] = f2b(x > 0.f ? x : 0.f);
    }
    *(ushort4*)&out[(size_t)d * 256 + fo] = o;
}

// ---------------- head ----------------

__global__ __launch_bounds__(256) void colsum_kernel(const unsigned short* __restrict__ x,
                                                     float* __restrict__ sums, int n) {
    int h = threadIdx.x;
    float acc = 0.0f;
    for (int r = blockIdx.x; r < n; r += gridDim.x) acc += b2f(x[(size_t)r * 256 + h]);
    atomicAdd(&sums[h], acc);
}

__global__ __launch_bounds__(64) void final_kernel(const float* __restrict__ sums,
                                                   const float* __restrict__ fcW,
                                                   const float* __restrict__ fcb,
                                                   float* __restrict__ out, float invN) {
    int lane = threadIdx.x;
    float p0 = 0.0f, p1 = 0.0f;
    for (int hh = lane; hh < 256; hh += 64) {
        float m = sums[hh];
        p0 += m * fcW[hh * 2 + 0];
        p1 += m * fcW[hh * 2 + 1];
    }
    for (int off = 32; off > 0; off >>= 1) {
        p0 += __shfl_down(p0, off);
        p1 += __shfl_down(p1, off);
    }
    if (lane == 0) {
        out[0] = p0 * invN + fcb[0];
        out[1] = p1 * invN + fcb[1];
    }
}

// ---------------- launch ----------------

extern "C" void kernel_launch(void* const* d_in, const int* in_sizes, int n_in,
                              void* d_out, int out_size, void* d_ws, size_t ws_size,
                              hipStream_t stream) {
    const float* node    = (const float*)d_in[0];
    const int*   edges   = (const int*)d_in[1];
    const float* eattr   = (const float*)d_in[2];
    const float* W1      = (const float*)d_in[3];
    const float* b1      = (const float*)d_in[4];
    const float* W_convs = (const float*)d_in[5];
    const float* b_convs = (const float*)d_in[6];
    const float* ln_g    = (const float*)d_in[7];
    const float* ln_b    = (const float*)d_in[8];
    const float* fc_W    = (const float*)d_in[9];
    const float* fc_b    = (const float*)d_in[10];
    float* out = (float*)d_out;

    const int H = in_sizes[4];           // 256
    const int F = in_sizes[3] / H;       // 128
    const int N = in_sizes[0] / F;       // 50000
    const int E = in_sizes[2];           // 1600000
    const int L = in_sizes[6] / H;       // 3

    const int* src = edges;
    const int* dst = edges + E;

    char* p = (char*)d_ws;
    auto alloc = [&](size_t bytes) {
        char* r = p;
        p += (bytes + 255) & ~(size_t)255;
        return r;
    };
    int nblk = (N + 255) / 256;
    // zeroed region: padded combo (64B/node) + colsums, contiguous
    unsigned long long* combo = (unsigned long long*)alloc((size_t)N * 64);
    float* colsums = (float*)alloc((size_t)H * 4);
    size_t zero_bytes = (size_t)((char*)colsums - (char*)combo) + (((size_t)H * 4 + 255) & ~(size_t)255);
    int*   blockhist = (int*)alloc((size_t)nblk * NBK * 4);
    int*   blockbase = (int*)alloc((size_t)nblk * NBK * 4);
    int*   perm    = (int*)alloc((size_t)N * 4);
    int*   posod   = (int*)alloc((size_t)N * 4);
    float* dinv    = (float*)alloc((size_t)N * 4);
    int*   row_ptr = (int*)alloc((size_t)(N + 1) * 4);
    unsigned int* edge = (unsigned int*)alloc(((size_t)E + 4 * (size_t)N + 64) * 4);
    unsigned short* Wt1 = (unsigned short*)alloc((size_t)H * F * 2);
    unsigned short* Wtc = (unsigned short*)alloc((size_t)L * H * H * 2);
    unsigned short* xw  = (unsigned short*)alloc((size_t)N * H * 2);   // sliced [8][N][32]
    unsigned short* preln = (unsigned short*)alloc((size_t)N * H * 2); // row-major [N][256]
    unsigned short* bufA  = (unsigned short*)alloc((size_t)N * H * 2); // bf16 x
    unsigned short* bufB  = (unsigned short*)alloc((size_t)N * H * 2); // bf16 x
    // aliases (dead before their slabs' first real use):
    int*            rank  = (int*)xw;                     // E*4 <= N*H*2
    unsigned short* nodeb = preln;                        // sliced [4][N][32] = N*128 shorts
    unsigned short* aggn  = preln + (size_t)N * F;        // bf16 [N][128] row-major

    hipMemsetAsync(combo, 0, zero_bytes, stream);

    int gE = (E + 255) / 256;
    rank_kernel<<<gE, 256, 0, stream>>>(dst, eattr, combo, rank, E);
    bin_hist_kernel<<<nblk, 256, 0, stream>>>(combo, blockhist, N);
    bin_offsets_kernel<<<1, NBK, 0, stream>>>(blockhist, blockbase, nblk);
    bin_scatter_kernel<<<nblk, 256, 0, stream>>>(combo, blockbase, perm, posod, N);
    scan_dinv_kernel<<<1, 1024, 0, stream>>>(combo, perm, row_ptr, dinv, N);
    selfpad_kernel<<<nblk, 256, 0, stream>>>(combo, row_ptr, posod, dinv, edge, N);
    scatter2_kernel<<<gE, 256, 0, stream>>>(src, dst, eattr, rank, row_ptr, posod, dinv, edge, E);

    cast_sliced_kernel<<<(N * (F / 4) + 255) / 256, 256, 0, stream>>>(node, perm, nodeb, N, F);
    wtrans_kernel<<<(F * H + 255) / 256, 256, 0, stream>>>(W1, Wt1, F, H);
    for (int i = 0; i < L; ++i)
        wtrans_kernel<<<(H * H + 255) / 256, 256, 0, stream>>>(
            W_convs + (size_t)i * H * H, Wtc + (size_t)i * H * H, H, H);

    int ngrp64 = (N + 63) / 64;
    int lngrid = (N + 3) / 4;
    int ggrid = (N + 63) / 64;

    // layer 1 (slot space): aggn = agg(node); x1 = aggn @ W1 + b1 (bf16)
    agg_grp<2><<<4 * ngrp64, 256, 0, stream>>>(nodeb, row_ptr, edge, aggn, N);
    gemm_n256<false><<<ggrid, 256, 0, stream>>>(aggn, Wt1, bufA, b1, N, F);

    unsigned short* x = bufA;
    unsigned short* other = bufB;
    for (int i = 0; i < L; ++i) {
        gemm_n256<true><<<ggrid, 256, 0, stream>>>(x, Wtc + (size_t)i * H * H, xw, nullptr, N, H);
        agg_grp<3><<<8 * ngrp64, 256, 0, stream>>>(xw, row_ptr, edge, preln, N);
        ln_res_relu<<<lngrid, 256, 0, stream>>>(preln, b_convs + (size_t)i * H,
                                                ln_g + (size_t)i * H, ln_b + (size_t)i * H,
                                                x, other, N);
        unsigned short* t = x; x = other; other = t;
    }

    colsum_kernel<<<256, 256, 0, stream>>>(x, colsums, N);
    final_kernel<<<1, 64, 0, stream>>>(colsums, fc_W, fc_b, out, 1.0f / (float)N);
}

// Round 13
// 794.641 us; speedup vs baseline: 1.6181x; 1.5024x over previous
//
#include <hip/hip_runtime.h>

#define EPS 1e-5f
#define FIXSCALE 8388608.0f   // 2^23 fixed-point for degree accumulation
#define NBK 64                // degree buckets (qc clamped)

typedef __attribute__((ext_vector_type(8))) short short8;
typedef __attribute__((ext_vector_type(4))) short short4v;
typedef __attribute__((ext_vector_type(4))) float float4v;
typedef __attribute__((ext_vector_type(2))) float float2v;
typedef __attribute__((ext_vector_type(8))) unsigned short ushort8;
typedef __attribute__((ext_vector_type(4))) unsigned int uint4v;

#if __has_builtin(__builtin_nontemporal_load)
#define NT_LOAD(p) __builtin_nontemporal_load(p)
#else
#define NT_LOAD(p) (*(p))
#endif

__device__ __forceinline__ unsigned short f2b(float f) {
    union { float f; unsigned u; } v; v.f = f;
    unsigned r = v.u + 0x7FFF + ((v.u >> 16) & 1);   // RNE
    return (unsigned short)(r >> 16);
}
__device__ __forceinline__ float b2f(unsigned short u) {
    union { unsigned u; float f; } v; v.u = ((unsigned)u) << 16;
    return v.f;
}

__device__ __forceinline__ int qbucket(int cnt) {
    int qc = ((cnt + 4) & ~3) >> 2;
    return qc < NBK - 1 ? qc : NBK - 1;
}

// ---------------- setup kernels ----------------

// ONE atomic per edge; combo padded to 1 node / 64B line
__global__ __launch_bounds__(256) void rank_kernel(const int* __restrict__ dst,
                                                   const float* __restrict__ w,
                                                   unsigned long long* __restrict__ combo,
                                                   int* __restrict__ rank, int E) {
    int e = blockIdx.x * 256 + threadIdx.x;
    if (e < E) {
        int d = dst[e];
        unsigned long long pack = (1ULL << 32) | (unsigned long long)(unsigned)(w[e] * FIXSCALE);
        unsigned long long old = atomicAdd(&combo[(size_t)d * 8], pack);
        rank[e] = (int)(old >> 32);
    }
}

// ---- contention-free counting sort by row quad-count (descending) ----

// per-block LDS histogram -> blockhist; LDS atomics only
__global__ __launch_bounds__(256) void bin_hist_kernel(const unsigned long long* __restrict__ combo,
                                                       int* __restrict__ blockhist, int n) {
    __shared__ int lh[NBK];
    int t = threadIdx.x;
    if (t < NBK) lh[t] = 0;
    __syncthreads();
    int d = blockIdx.x * 256 + t;
    if (d < n) {
        int cnt = (int)(combo[(size_t)d * 8] >> 32);
        atomicAdd(&lh[qbucket(cnt)], 1);
    }
    __syncthreads();
    if (t < NBK) blockhist[blockIdx.x * NBK + t] = lh[t];
}

// one block PER BUCKET: exclusive prefix of its per-block counts + bucket total
__global__ __launch_bounds__(256) void bin_prescan_kernel(const int* __restrict__ blockhist,
                                                          int* __restrict__ blockpre,
                                                          int* __restrict__ tot, int nblk) {
    int bkt = blockIdx.x;
    int t = threadIdx.x, lane = t & 63, w = t >> 6;
    __shared__ int wsum[4];
    __shared__ int s_carry;
    if (t == 0) s_carry = 0;
    __syncthreads();
    for (int base = 0; base < nblk; base += 256) {
        int i = base + t;
        int v = (i < nblk) ? blockhist[i * NBK + bkt] : 0;
        int x = v;
        for (int off = 1; off < 64; off <<= 1) {
            int u = __shfl_up(x, off);
            if (lane >= off) x += u;
        }
        if (lane == 63) wsum[w] = x;
        __syncthreads();
        if (t == 0) {
            int a = wsum[0];
            wsum[0] = 0;
            for (int k = 1; k < 4; ++k) { int b = wsum[k]; wsum[k] = a; a += b; }
            wsum[0] = 0;   // exclusive across waves (recompute: wsum[k] = sum of waves < k)
        }
        __syncthreads();
        int carry = s_carry;
        int woff = wsum[w];
        if (i < nblk) blockpre[i * NBK + bkt] = carry + woff + x - v;
        __syncthreads();
        if (t == 255) s_carry = carry + woff + x;   // last wave's inclusive end = chunk total
        __syncthreads();
    }
    if (t == 0) tot[bkt] = s_carry;
}

// single wave: base[b] = sum_{b' > b} tot[b']  (descending buckets first)
__global__ __launch_bounds__(64) void bin_suffix_kernel(const int* __restrict__ tot,
                                                        int* __restrict__ base) {
    int t = threadIdx.x;
    int v = tot[t];
    int s = v;
    for (int off = 1; off < 64; off <<= 1) {
        int u = __shfl_down(s, off);
        if (t + off < 64) s += u;
    }
    base[t] = s - v;
}

// assign slots via LDS cursors (no global atomics)
__global__ __launch_bounds__(256) void bin_scatter_kernel(const unsigned long long* __restrict__ combo,
                                                          const int* __restrict__ base,
                                                          const int* __restrict__ blockpre,
                                                          int* __restrict__ perm,
                                                          int* __restrict__ posod, int n) {
    __shared__ int lcur[NBK];
    int t = threadIdx.x;
    if (t < NBK) lcur[t] = base[t] + blockpre[blockIdx.x * NBK + t];
    __syncthreads();
    int d = blockIdx.x * 256 + t;
    if (d < n) {
        int cnt = (int)(combo[(size_t)d * 8] >> 32);
        int pos = atomicAdd(&lcur[qbucket(cnt)], 1);
        perm[pos] = d;
        posod[d] = pos;
    }
}

// row_ptr over permuted slots; dinv per original node
__global__ __launch_bounds__(1024) void scan_dinv_kernel(const unsigned long long* __restrict__ combo,
                                                         const int* __restrict__ perm,
                                                         int* __restrict__ row_ptr,
                                                         float* __restrict__ dinv, int n) {
    int tid = threadIdx.x, lane = tid & 63, w = tid >> 6;
    __shared__ int wsum[16];
    __shared__ int s_carry;
    if (tid == 0) s_carry = 0;
    __syncthreads();
    for (int base = 0; base < n; base += 1024) {
        int i = base + tid;
        int v = 0;
        if (i < n) {
            unsigned long long cb = combo[(size_t)i * 8];
            float degv = (float)(unsigned)(cb & 0xffffffffULL) * (1.0f / FIXSCALE);
            dinv[i] = rsqrtf(degv + 1.0f);
            int cntp = (int)(combo[(size_t)perm[i] * 8] >> 32);
            v = (cntp + 4) & ~3;
        }
        int x = v;
        for (int off = 1; off < 64; off <<= 1) {
            int t = __shfl_up(x, off);
            if (lane >= off) x += t;
        }
        if (lane == 63) wsum[w] = x;
        __syncthreads();
        if (w == 0 && lane < 16) {
            int s = wsum[lane];
            for (int off = 1; off < 16; off <<= 1) {
                int t = __shfl_up(s, off, 16);
                if (lane >= off) s += t;
            }
            wsum[lane] = s;
        }
        __syncthreads();
        int carry = s_carry;
        int woff = (w > 0) ? wsum[w - 1] : 0;
        if (i < n) row_ptr[i + 1] = carry + woff + x;
        __syncthreads();
        if (tid == 0) s_carry = carry + wsum[15];
        __syncthreads();
    }
    if (tid == 0) row_ptr[0] = 0;
}

// self-edge (slot 0, weight dinv^2, src = own slot) + zero-weight pads
__global__ __launch_bounds__(256) void selfpad_kernel(const unsigned long long* __restrict__ combo,
                                                      const int* __restrict__ row_ptr,
                                                      const int* __restrict__ posod,
                                                      const float* __restrict__ dinv,
                                                      unsigned int* __restrict__ edge, int n) {
    int d = blockIdx.x * 256 + threadIdx.x;
    if (d < n) {
        int cnt = (int)(combo[(size_t)d * 8] >> 32);
        int slot = posod[d];
        int j0 = row_ptr[slot], j1 = row_ptr[slot + 1];
        float di = dinv[d];
        edge[j0] = ((unsigned)f2b(di * di) << 16) | (unsigned)slot;
        for (int j = j0 + 1 + cnt; j < j1; ++j) edge[j] = (unsigned)slot;  // w = +0
    }
}

// atomic-free scatter into permuted CSR; record = wn(bf16)<<16 | srcslot(u16)
__global__ __launch_bounds__(256) void scatter2_kernel(
    const int* __restrict__ src, const int* __restrict__ dst,
    const float* __restrict__ w, const int* __restrict__ rank,
    const int* __restrict__ row_ptr, const int* __restrict__ posod,
    const float* __restrict__ dinv, unsigned int* __restrict__ edge, int E) {
    int e = blockIdx.x * 256 + threadIdx.x;
    if (e < E) {
        int d = dst[e], s = src[e];
        float wn = dinv[s] * w[e] * dinv[d];
        edge[row_ptr[posod[d]] + 1 + rank[e]] = ((unsigned)f2b(wn) << 16) | (unsigned)posod[s];
    }
}

// node f32 [N][F] (original order) -> bf16 slice-major [F/32][n][32] in SLOT order
__global__ __launch_bounds__(256) void cast_sliced_kernel(const float* __restrict__ in,
                                                          const int* __restrict__ perm,
                                                          unsigned short* __restrict__ out,
                                                          int n, int F) {
    int idx = blockIdx.x * 256 + threadIdx.x;
    if (idx < n * (F / 4)) {
        int f4 = idx * 4;
        int slot = f4 / F, f = f4 - slot * F;
        float4 v = *(const float4*)&in[(size_t)perm[slot] * F + f];
        short4v s = (short4v){(short)f2b(v.x), (short)f2b(v.y), (short)f2b(v.z), (short)f2b(v.w)};
        *(short4v*)&out[((size_t)(f >> 5) * n + slot) * 32 + (f & 31)] = s;
    }
}

__global__ __launch_bounds__(256) void wtrans_kernel(const float* __restrict__ W,
                                                     unsigned short* __restrict__ Wt,
                                                     int K, int Nc) {
    int o = blockIdx.x * 256 + threadIdx.x;
    if (o < K * Nc) {
        int n = o / K, k = o - n * K;
        Wt[o] = f2b(W[(size_t)k * Nc + n]);
    }
}

// ---------------- bf16 MFMA GEMM, full-N strip: C[M,256] = A[M,K](bf16) @ Bt[256,K]^T ----

#define GST 88

template <bool SLICEOUT>
__global__ __launch_bounds__(256) void gemm_n256(const unsigned short* __restrict__ A,
                                                 const unsigned short* __restrict__ Bt,
                                                 unsigned short* __restrict__ Cout,
                                                 const float* __restrict__ bias,
                                                 int M, int K) {
    __shared__ __align__(16) short As[64 * GST];
    __shared__ __align__(16) short Bs[256 * GST];
    int t = threadIdx.x;
    int lane = t & 63, w = t >> 6;
    int quad = lane >> 4, l16 = lane & 15;
    int row0 = blockIdx.x * 64;

    float4v acc[16];
#pragma unroll
    for (int c = 0; c < 16; ++c) acc[c] = (float4v){0.f, 0.f, 0.f, 0.f};

    int arow = t >> 2, ak16 = (t & 3) * 16;
    int bcol0 = t >> 2, bko = (t & 3) * 16;

    for (int k_outer = 0; k_outer < K; k_outer += 64) {
        bool rowok = (row0 + arow) < M;
        const unsigned short* ap = &A[(size_t)(row0 + arow) * K + k_outer + ak16];
        uint4 z = make_uint4(0, 0, 0, 0);
        uint4 u0 = rowok ? *(const uint4*)ap : z;
        uint4 u1 = rowok ? *(const uint4*)(ap + 8) : z;
        *(uint4*)&As[arow * GST + ak16] = u0;
        *(uint4*)&As[arow * GST + ak16 + 8] = u1;
#pragma unroll
        for (int cb = 0; cb < 4; ++cb) {
            int col = bcol0 + 64 * cb;
            const unsigned short* bp = &Bt[(size_t)col * K + k_outer + bko];
#pragma unroll
            for (int u = 0; u < 2; ++u)
                *(uint4*)&Bs[col * GST + bko + u * 8] = *(const uint4*)&bp[u * 8];
        }
        __syncthreads();
#pragma unroll
        for (int k0 = 0; k0 < 64; k0 += 32) {
            short8 a = *(const short8*)&As[(w * 16 + l16) * GST + k0 + quad * 8];
#pragma unroll
            for (int c = 0; c < 16; ++c) {
                short8 b = *(const short8*)&Bs[(c * 16 + l16) * GST + k0 + quad * 8];
                acc[c] = __builtin_amdgcn_mfma_f32_16x16x32_bf16(a, b, acc[c], 0, 0, 0);
            }
        }
        __syncthreads();
    }
#pragma unroll
    for (int c = 0; c < 16; ++c) {
        int col = c * 16 + l16;
        float bcol = (!SLICEOUT) ? bias[col] : 0.0f;
#pragma unroll
        for (int r = 0; r < 4; ++r) {
            int row = row0 + w * 16 + quad * 4 + r;
            if (row < M) {
                if (SLICEOUT)
                    Cout[((size_t)(c >> 1) * M + row) * 32 + ((c & 1) << 4) + l16] = f2b(acc[c][r]);
                else
                    Cout[(size_t)row * 256 + col] = f2b(acc[c][r] + bcol);
            }
        }
    }
}

// ---------------- aggregation: 4-lane group per slot, slice-major table, LDS edges ------
// Slots are degree-sorted (descending) -> all 16 groups of a wave have near-equal row
// lengths: no exec-divergence. Everything (table rows, edge src ids, output rows) is in
// slot space. slice = blockIdx & mask -> XCD-resident 3.2MB slice. 16 KB LDS edge stage.

#define CAPQ 1024   // 4096 edges, 16 KB LDS

template <int CSH>
__global__ __launch_bounds__(256) void agg_grp(
    const unsigned short* __restrict__ tab0, const int* __restrict__ row_ptr,
    const unsigned int* __restrict__ edge, unsigned short* __restrict__ outb, int n) {
    __shared__ uint4v eq[CAPQ];
    int b = blockIdx.x;
    int s = b & ((1 << CSH) - 1);
    int grp = b >> CSH;
    int t = threadIdx.x;
    int d0 = grp * 64;
    int d = d0 + (t >> 2);

    const uint4v* e4p = (const uint4v*)edge;
    int qbase = row_ptr[d0] >> 2;
    int dmax = d0 + 64 < n ? d0 + 64 : n;
    int qcnt = (row_ptr[dmax] >> 2) - qbase;
    int qstage = qcnt < CAPQ ? qcnt : CAPQ;
    for (int i = t; i < qstage; i += 256) eq[i] = NT_LOAD(&e4p[qbase + i]);
    __syncthreads();

    if (d >= n) return;
    int fo = (t & 3) << 3;                    // feature offset within the 32-wide slice
    const unsigned short* tab = tab0 + (size_t)s * n * 32;

    int j = row_ptr[d] >> 2, j1 = row_ptr[d + 1] >> 2;
    int jmid = j1 < qbase + CAPQ ? j1 : qbase + CAPQ;

    float2v a2[4];
#pragma unroll
    for (int k = 0; k < 4; ++k) a2[k] = (float2v){0.f, 0.f};

    auto process = [&](uint4v e4) {
#pragma unroll
        for (int u = 0; u < 4; ++u) {
            unsigned e = e4[u];
            float wq = __int_as_float((int)(e & 0xffff0000u));
            float2v w2 = {wq, wq};
            unsigned off = ((e & 0xffffu) << 5) + (unsigned)fo;
            uint4 rr = *(const uint4*)(tab + off);
            unsigned uu0 = rr.x, uu1 = rr.y, uu2 = rr.z, uu3 = rr.w;
            float2v f0 = {__uint_as_float(uu0 << 16), __uint_as_float(uu0 & 0xffff0000u)};
            float2v f1 = {__uint_as_float(uu1 << 16), __uint_as_float(uu1 & 0xffff0000u)};
            float2v f2 = {__uint_as_float(uu2 << 16), __uint_as_float(uu2 & 0xffff0000u)};
            float2v f3 = {__uint_as_float(uu3 << 16), __uint_as_float(uu3 & 0xffff0000u)};
            a2[0] += f0 * w2;
            a2[1] += f1 * w2;
            a2[2] += f2 * w2;
            a2[3] += f3 * w2;
        }
    };

    for (; j + 2 <= jmid; j += 2) {
        uint4v e4a = eq[j - qbase];
        uint4v e4b = eq[j + 1 - qbase];
        process(e4a);
        process(e4b);
    }
    if (j < jmid) { process(eq[j - qbase]); ++j; }
    for (; j < j1; ++j) process(NT_LOAD(&e4p[j]));   // overflow fallback (first blocks only)

    ushort8 o;
#pragma unroll
    for (int k = 0; k < 4; ++k) {
        o[2 * k] = f2b(a2[k].x);
        o[2 * k + 1] = f2b(a2[k].y);
    }
    *(ushort8*)(outb + ((size_t)d << (5 + CSH)) + (s << 5) + fo) = o;
}

// ---------------- bias + LayerNorm + residual + ReLU (bf16 in, bf16 out) ----------------

__global__ __launch_bounds__(256) void ln_res_relu(
    const unsigned short* __restrict__ preln, const float* __restrict__ bias,
    const float* __restrict__ g, const float* __restrict__ lb,
    const unsigned short* __restrict__ res, unsigned short* __restrict__ out, int n) {
    int wv = __builtin_amdgcn_readfirstlane(threadIdx.x >> 6);
    int d = blockIdx.x * 4 + wv;
    if (d >= n) return;
    int l = threadIdx.x & 63;
    int fo = l * 4;
    ushort4 pv = *(const ushort4*)&preln[(size_t)d * 256 + fo];
    float4 bb = *(const float4*)&bias[fo];
    float v[4] = {b2f(pv.x) + bb.x, b2f(pv.y) + bb.y, b2f(pv.z) + bb.z, b2f(pv.w) + bb.w};
    float s4 = v[0] + v[1] + v[2] + v[3];
#pragma unroll
    for (int off = 1; off < 64; off <<= 1) s4 += __shfl_xor(s4, off);
    float mu = s4 * (1.0f / 256.0f);
    float dv[4];
    float qs = 0.f;
#pragma unroll
    for (int j = 0; j < 4; ++j) { dv[j] = v[j] - mu; qs += dv[j] * dv[j]; }
#pragma unroll
    for (int off = 1; off < 64; off <<= 1) qs += __shfl_xor(qs, off);
    float rs = rsqrtf(qs * (1.0f / 256.0f) + EPS);

    float4 gg = *(const float4*)&g[fo];
    float4 lbv = *(const float4*)&lb[fo];
    ushort4 rr4 = *(const ushort4*)&res[(size_t)d * 256 + fo];
    float ggv[4] = {gg.x, gg.y, gg.z, gg.w};
    float lbvv[4] = {lbv.x, lbv.y, lbv.z, lbv.w};
    float rrv[4] = {b2f(rr4.x), b2f(rr4.y), b2f(rr4.z), b2f(rr4.w)};
    ushort4 o;
    unsigned short* op = (unsigned short*)&o;
#pragma unroll
    for (int j = 0; j < 4; ++j) {
        float x = dv[j] * rs * ggv[j] + lbvv[j] + rrv[j];
        op[j] = f2b(x > 0.f ? x : 0.f);
    }
    *(ushort4*)&out[(size_t)d * 256 + fo] = o;
}

// ---------------- head ----------------

__global__ __launch_bounds__(256) void colsum_kernel(const unsigned short* __restrict__ x,
                                                     float* __restrict__ sums, int n) {
    int h = threadIdx.x;
    float acc = 0.0f;
    for (int r = blockIdx.x; r < n; r += gridDim.x) acc += b2f(x[(size_t)r * 256 + h]);
    atomicAdd(&sums[h], acc);
}

__global__ __launch_bounds__(64) void final_kernel(const float* __restrict__ sums,
                                                   const float* __restrict__ fcW,
                                                   const float* __restrict__ fcb,
                                                   float* __restrict__ out, float invN) {
    int lane = threadIdx.x;
    float p0 = 0.0f, p1 = 0.0f;
    for (int hh = lane; hh < 256; hh += 64) {
        float m = sums[hh];
        p0 += m * fcW[hh * 2 + 0];
        p1 += m * fcW[hh * 2 + 1];
    }
    for (int off = 32; off > 0; off >>= 1) {
        p0 += __shfl_down(p0, off);
        p1 += __shfl_down(p1, off);
    }
    if (lane == 0) {
        out[0] = p0 * invN + fcb[0];
        out[1] = p1 * invN + fcb[1];
    }
}

// ---------------- launch ----------------

extern "C" void kernel_launch(void* const* d_in, const int* in_sizes, int n_in,
                              void* d_out, int out_size, void* d_ws, size_t ws_size,
                              hipStream_t stream) {
    const float* node    = (const float*)d_in[0];
    const int*   edges   = (const int*)d_in[1];
    const float* eattr   = (const float*)d_in[2];
    const float* W1      = (const float*)d_in[3];
    const float* b1      = (const float*)d_in[4];
    const float* W_convs = (const float*)d_in[5];
    const float* b_convs = (const float*)d_in[6];
    const float* ln_g    = (const float*)d_in[7];
    const float* ln_b    = (const float*)d_in[8];
    const float* fc_W    = (const float*)d_in[9];
    const float* fc_b    = (const float*)d_in[10];
    float* out = (float*)d_out;

    const int H = in_sizes[4];           // 256
    const int F = in_sizes[3] / H;       // 128
    const int N = in_sizes[0] / F;       // 50000
    const int E = in_sizes[2];           // 1600000
    const int L = in_sizes[6] / H;       // 3

    const int* src = edges;
    const int* dst = edges + E;

    char* p = (char*)d_ws;
    auto alloc = [&](size_t bytes) {
        char* r = p;
        p += (bytes + 255) & ~(size_t)255;
        return r;
    };
    int nblk = (N + 255) / 256;
    // zeroed region: padded combo (64B/node) + colsums, contiguous
    unsigned long long* combo = (unsigned long long*)alloc((size_t)N * 64);
    float* colsums = (float*)alloc((size_t)H * 4);
    size_t zero_bytes = (size_t)((char*)colsums - (char*)combo) + (((size_t)H * 4 + 255) & ~(size_t)255);
    int*   blockhist = (int*)alloc((size_t)nblk * NBK * 4);
    int*   blockpre  = (int*)alloc((size_t)nblk * NBK * 4);
    int*   tot       = (int*)alloc((size_t)NBK * 4);
    int*   bbase     = (int*)alloc((size_t)NBK * 4);
    int*   perm    = (int*)alloc((size_t)N * 4);
    int*   posod   = (int*)alloc((size_t)N * 4);
    float* dinv    = (float*)alloc((size_t)N * 4);
    int*   row_ptr = (int*)alloc((size_t)(N + 1) * 4);
    unsigned int* edge = (unsigned int*)alloc(((size_t)E + 4 * (size_t)N + 64) * 4);
    unsigned short* Wt1 = (unsigned short*)alloc((size_t)H * F * 2);
    unsigned short* Wtc = (unsigned short*)alloc((size_t)L * H * H * 2);
    unsigned short* xw  = (unsigned short*)alloc((size_t)N * H * 2);   // sliced [8][N][32]
    unsigned short* preln = (unsigned short*)alloc((size_t)N * H * 2); // row-major [N][256]
    unsigned short* bufA  = (unsigned short*)alloc((size_t)N * H * 2); // bf16 x
    unsigned short* bufB  = (unsigned short*)alloc((size_t)N * H * 2); // bf16 x
    // aliases (dead before their slabs' first real use):
    int*            rank  = (int*)xw;                     // E*4 <= N*H*2
    unsigned short* nodeb = preln;                        // sliced [4][N][32] = N*128 shorts
    unsigned short* aggn  = preln + (size_t)N * F;        // bf16 [N][128] row-major

    hipMemsetAsync(combo, 0, zero_bytes, stream);

    int gE = (E + 255) / 256;
    rank_kernel<<<gE, 256, 0, stream>>>(dst, eattr, combo, rank, E);
    bin_hist_kernel<<<nblk, 256, 0, stream>>>(combo, blockhist, N);
    bin_prescan_kernel<<<NBK, 256, 0, stream>>>(blockhist, blockpre, tot, nblk);
    bin_suffix_kernel<<<1, 64, 0, stream>>>(tot, bbase);
    bin_scatter_kernel<<<nblk, 256, 0, stream>>>(combo, bbase, blockpre, perm, posod, N);
    scan_dinv_kernel<<<1, 1024, 0, stream>>>(combo, perm, row_ptr, dinv, N);
    selfpad_kernel<<<nblk, 256, 0, stream>>>(combo, row_ptr, posod, dinv, edge, N);
    scatter2_kernel<<<gE, 256, 0, stream>>>(src, dst, eattr, rank, row_ptr, posod, dinv, edge, E);

    cast_sliced_kernel<<<(N * (F / 4) + 255) / 256, 256, 0, stream>>>(node, perm, nodeb, N, F);
    wtrans_kernel<<<(F * H + 255) / 256, 256, 0, stream>>>(W1, Wt1, F, H);
    for (int i = 0; i < L; ++i)
        wtrans_kernel<<<(H * H + 255) / 256, 256, 0, stream>>>(
            W_convs + (size_t)i * H * H, Wtc + (size_t)i * H * H, H, H);

    int ngrp64 = (N + 63) / 64;
    int lngrid = (N + 3) / 4;
    int ggrid = (N + 63) / 64;

    // layer 1 (slot space): aggn = agg(node); x1 = aggn @ W1 + b1 (bf16)
    agg_grp<2><<<4 * ngrp64, 256, 0, stream>>>(nodeb, row_ptr, edge, aggn, N);
    gemm_n256<false><<<ggrid, 256, 0, stream>>>(aggn, Wt1, bufA, b1, N, F);

    unsigned short* x = bufA;
    unsigned short* other = bufB;
    for (int i = 0; i < L; ++i) {
        gemm_n256<true><<<ggrid, 256, 0, stream>>>(x, Wtc + (size_t)i * H * H, xw, nullptr, N, H);
        agg_grp<3><<<8 * ngrp64, 256, 0, stream>>>(xw, row_ptr, edge, preln, N);
        ln_res_relu<<<lngrid, 256, 0, stream>>>(preln, b_convs + (size_t)i * H,
                                                ln_g + (size_t)i * H, ln_b + (size_t)i * H,
                                                x, other, N);
        unsigned short* t = x; x = other; other = t;
    }

    colsum_kernel<<<256, 256, 0, stream>>>(x, colsums, N);
    final_kernel<<<1, 64, 0, stream>>>(colsums, fc_W, fc_b, out, 1.0f / (float)N);
}

// Round 14
// 732.365 us; speedup vs baseline: 1.7557x; 1.0850x over previous
//
#include <hip/hip_runtime.h>

#define EPS 1e-5f
#define FIXSCALE 8388608.0f   // 2^23 fixed-point for degree accumulation
#define NBK 64                // degree buckets (qc clamped)

typedef __attribute__((ext_vector_type(8))) short short8;
typedef __attribute__((ext_vector_type(4))) short short4v;
typedef __attribute__((ext_vector_type(4))) float float4v;
typedef __attribute__((ext_vector_type(2))) float float2v;
typedef __attribute__((ext_vector_type(8))) unsigned short ushort8;
typedef __attribute__((ext_vector_type(4))) unsigned int uint4v;

#if __has_builtin(__builtin_nontemporal_load)
#define NT_LOAD(p) __builtin_nontemporal_load(p)
#else
#define NT_LOAD(p) (*(p))
#endif

__device__ __forceinline__ unsigned short f2b(float f) {
    union { float f; unsigned u; } v; v.f = f;
    unsigned r = v.u + 0x7FFF + ((v.u >> 16) & 1);   // RNE
    return (unsigned short)(r >> 16);
}
__device__ __forceinline__ float b2f(unsigned short u) {
    union { unsigned u; float f; } v; v.u = ((unsigned)u) << 16;
    return v.f;
}

__device__ __forceinline__ int qbucket(int cnt) {
    int qc = ((cnt + 4) & ~3) >> 2;
    return qc < NBK - 1 ? qc : NBK - 1;
}

// ---------------- setup kernels ----------------

// ONE atomic per edge; combo padded to 1 node / 64B line
__global__ __launch_bounds__(256) void rank_kernel(const int* __restrict__ dst,
                                                   const float* __restrict__ w,
                                                   unsigned long long* __restrict__ combo,
                                                   int* __restrict__ rank, int E) {
    int e = blockIdx.x * 256 + threadIdx.x;
    if (e < E) {
        int d = dst[e];
        unsigned long long pack = (1ULL << 32) | (unsigned long long)(unsigned)(w[e] * FIXSCALE);
        unsigned long long old = atomicAdd(&combo[(size_t)d * 8], pack);
        rank[e] = (int)(old >> 32);
    }
}

// dinv per original node (parallel, grid-stride)
__global__ __launch_bounds__(256) void dinv_kernel(const unsigned long long* __restrict__ combo,
                                                   float* __restrict__ dinv, int n) {
    int d = blockIdx.x * 256 + threadIdx.x;
    if (d < n) {
        float degv = (float)(unsigned)(combo[(size_t)d * 8] & 0xffffffffULL) * (1.0f / FIXSCALE);
        dinv[d] = rsqrtf(degv + 1.0f);
    }
}

// ---- contention-free counting sort by row quad-count (descending) ----

// per-block LDS histogram -> blockhist; LDS atomics only
__global__ __launch_bounds__(256) void bin_hist_kernel(const unsigned long long* __restrict__ combo,
                                                       int* __restrict__ blockhist, int n) {
    __shared__ int lh[NBK];
    int t = threadIdx.x;
    if (t < NBK) lh[t] = 0;
    __syncthreads();
    int d = blockIdx.x * 256 + t;
    if (d < n) {
        int cnt = (int)(combo[(size_t)d * 8] >> 32);
        atomicAdd(&lh[qbucket(cnt)], 1);
    }
    __syncthreads();
    if (t < NBK) blockhist[blockIdx.x * NBK + t] = lh[t];
}

// one block PER BUCKET: exclusive prefix of its per-block counts + bucket total
__global__ __launch_bounds__(256) void bin_prescan_kernel(const int* __restrict__ blockhist,
                                                          int* __restrict__ blockpre,
                                                          int* __restrict__ tot, int nblk) {
    int bkt = blockIdx.x;
    int t = threadIdx.x, lane = t & 63, w = t >> 6;
    __shared__ int wsum[4];
    __shared__ int s_carry;
    if (t == 0) s_carry = 0;
    __syncthreads();
    for (int base = 0; base < nblk; base += 256) {
        int i = base + t;
        int v = (i < nblk) ? blockhist[i * NBK + bkt] : 0;
        int x = v;
        for (int off = 1; off < 64; off <<= 1) {
            int u = __shfl_up(x, off);
            if (lane >= off) x += u;
        }
        if (lane == 63) wsum[w] = x;
        __syncthreads();
        if (t == 0) {
            int a = wsum[0];
            wsum[0] = 0;
            for (int k = 1; k < 4; ++k) { int b = wsum[k]; wsum[k] = a; a += b; }
            wsum[0] = 0;
        }
        __syncthreads();
        int carry = s_carry;
        int woff = wsum[w];
        if (i < nblk) blockpre[i * NBK + bkt] = carry + woff + x - v;
        __syncthreads();
        if (t == 255) s_carry = carry + woff + x;
        __syncthreads();
    }
    if (t == 0) tot[bkt] = s_carry;
}

// single wave: base[b] = sum_{b' > b} tot[b']  (descending buckets first)
__global__ __launch_bounds__(64) void bin_suffix_kernel(const int* __restrict__ tot,
                                                        int* __restrict__ base) {
    int t = threadIdx.x;
    int v = tot[t];
    int s = v;
    for (int off = 1; off < 64; off <<= 1) {
        int u = __shfl_down(s, off);
        if (t + off < 64) s += u;
    }
    base[t] = s - v;
}

// assign slots via LDS cursors; also record each slot's padded quad length (linear later)
__global__ __launch_bounds__(256) void bin_scatter_kernel(const unsigned long long* __restrict__ combo,
                                                          const int* __restrict__ base,
                                                          const int* __restrict__ blockpre,
                                                          int* __restrict__ perm,
                                                          int* __restrict__ posod,
                                                          int* __restrict__ qlen, int n) {
    __shared__ int lcur[NBK];
    int t = threadIdx.x;
    if (t < NBK) lcur[t] = base[t] + blockpre[blockIdx.x * NBK + t];
    __syncthreads();
    int d = blockIdx.x * 256 + t;
    if (d < n) {
        int cnt = (int)(combo[(size_t)d * 8] >> 32);
        int pos = atomicAdd(&lcur[qbucket(cnt)], 1);
        perm[pos] = d;
        posod[d] = pos;
        qlen[pos] = (cnt + 4) & ~3;
    }
}

// row_ptr over permuted slots: linear scan of qlen (single block, coalesced)
__global__ __launch_bounds__(1024) void scan_kernel(const int* __restrict__ qlen,
                                                    int* __restrict__ row_ptr, int n) {
    int tid = threadIdx.x, lane = tid & 63, w = tid >> 6;
    __shared__ int wsum[16];
    __shared__ int s_carry;
    if (tid == 0) s_carry = 0;
    __syncthreads();
    for (int base = 0; base < n; base += 1024) {
        int i = base + tid;
        int v = (i < n) ? qlen[i] : 0;
        int x = v;
        for (int off = 1; off < 64; off <<= 1) {
            int t = __shfl_up(x, off);
            if (lane >= off) x += t;
        }
        if (lane == 63) wsum[w] = x;
        __syncthreads();
        if (w == 0 && lane < 16) {
            int s = wsum[lane];
            for (int off = 1; off < 16; off <<= 1) {
                int t = __shfl_up(s, off, 16);
                if (lane >= off) s += t;
            }
            wsum[lane] = s;
        }
        __syncthreads();
        int carry = s_carry;
        int woff = (w > 0) ? wsum[w - 1] : 0;
        if (i < n) row_ptr[i + 1] = carry + woff + x;
        __syncthreads();
        if (tid == 0) s_carry = carry + wsum[15];
        __syncthreads();
    }
    if (tid == 0) row_ptr[0] = 0;
}

// self-edge (slot 0, weight dinv^2, src = own slot) + zero-weight pads
__global__ __launch_bounds__(256) void selfpad_kernel(const unsigned long long* __restrict__ combo,
                                                      const int* __restrict__ row_ptr,
                                                      const int* __restrict__ posod,
                                                      const float* __restrict__ dinv,
                                                      unsigned int* __restrict__ edge, int n) {
    int d = blockIdx.x * 256 + threadIdx.x;
    if (d < n) {
        int cnt = (int)(combo[(size_t)d * 8] >> 32);
        int slot = posod[d];
        int j0 = row_ptr[slot], j1 = row_ptr[slot + 1];
        float di = dinv[d];
        edge[j0] = ((unsigned)f2b(di * di) << 16) | (unsigned)slot;
        for (int j = j0 + 1 + cnt; j < j1; ++j) edge[j] = (unsigned)slot;  // w = +0
    }
}

// atomic-free scatter into permuted CSR; record = wn(bf16)<<16 | srcslot(u16)
__global__ __launch_bounds__(256) void scatter2_kernel(
    const int* __restrict__ src, const int* __restrict__ dst,
    const float* __restrict__ w, const int* __restrict__ rank,
    const int* __restrict__ row_ptr, const int* __restrict__ posod,
    const float* __restrict__ dinv, unsigned int* __restrict__ edge, int E) {
    int e = blockIdx.x * 256 + threadIdx.x;
    if (e < E) {
        int d = dst[e], s = src[e];
        float wn = dinv[s] * w[e] * dinv[d];
        edge[row_ptr[posod[d]] + 1 + rank[e]] = ((unsigned)f2b(wn) << 16) | (unsigned)posod[s];
    }
}

// node f32 [N][F] (original order) -> bf16 slice-major [F/32][n][32] in SLOT order
__global__ __launch_bounds__(256) void cast_sliced_kernel(const float* __restrict__ in,
                                                          const int* __restrict__ perm,
                                                          unsigned short* __restrict__ out,
                                                          int n, int F) {
    int idx = blockIdx.x * 256 + threadIdx.x;
    if (idx < n * (F / 4)) {
        int f4 = idx * 4;
        int slot = f4 / F, f = f4 - slot * F;
        float4 v = *(const float4*)&in[(size_t)perm[slot] * F + f];
        short4v s = (short4v){(short)f2b(v.x), (short)f2b(v.y), (short)f2b(v.z), (short)f2b(v.w)};
        *(short4v*)&out[((size_t)(f >> 5) * n + slot) * 32 + (f & 31)] = s;
    }
}

__global__ __launch_bounds__(256) void wtrans_kernel(const float* __restrict__ W,
                                                     unsigned short* __restrict__ Wt,
                                                     int K, int Nc) {
    int o = blockIdx.x * 256 + threadIdx.x;
    if (o < K * Nc) {
        int n = o / K, k = o - n * K;
        Wt[o] = f2b(W[(size_t)k * Nc + n]);
    }
}

// ---------------- bf16 MFMA GEMM, full-N strip: C[M,256] = A[M,K](bf16) @ Bt[256,K]^T ----

#define GST 88

template <bool SLICEOUT>
__global__ __launch_bounds__(256) void gemm_n256(const unsigned short* __restrict__ A,
                                                 const unsigned short* __restrict__ Bt,
                                                 unsigned short* __restrict__ Cout,
                                                 const float* __restrict__ bias,
                                                 int M, int K) {
    __shared__ __align__(16) short As[64 * GST];
    __shared__ __align__(16) short Bs[256 * GST];
    int t = threadIdx.x;
    int lane = t & 63, w = t >> 6;
    int quad = lane >> 4, l16 = lane & 15;
    int row0 = blockIdx.x * 64;

    float4v acc[16];
#pragma unroll
    for (int c = 0; c < 16; ++c) acc[c] = (float4v){0.f, 0.f, 0.f, 0.f};

    int arow = t >> 2, ak16 = (t & 3) * 16;
    int bcol0 = t >> 2, bko = (t & 3) * 16;

    for (int k_outer = 0; k_outer < K; k_outer += 64) {
        bool rowok = (row0 + arow) < M;
        const unsigned short* ap = &A[(size_t)(row0 + arow) * K + k_outer + ak16];
        uint4 z = make_uint4(0, 0, 0, 0);
        uint4 u0 = rowok ? *(const uint4*)ap : z;
        uint4 u1 = rowok ? *(const uint4*)(ap + 8) : z;
        *(uint4*)&As[arow * GST + ak16] = u0;
        *(uint4*)&As[arow * GST + ak16 + 8] = u1;
#pragma unroll
        for (int cb = 0; cb < 4; ++cb) {
            int col = bcol0 + 64 * cb;
            const unsigned short* bp = &Bt[(size_t)col * K + k_outer + bko];
#pragma unroll
            for (int u = 0; u < 2; ++u)
                *(uint4*)&Bs[col * GST + bko + u * 8] = *(const uint4*)&bp[u * 8];
        }
        __syncthreads();
#pragma unroll
        for (int k0 = 0; k0 < 64; k0 += 32) {
            short8 a = *(const short8*)&As[(w * 16 + l16) * GST + k0 + quad * 8];
#pragma unroll
            for (int c = 0; c < 16; ++c) {
                short8 b = *(const short8*)&Bs[(c * 16 + l16) * GST + k0 + quad * 8];
                acc[c] = __builtin_amdgcn_mfma_f32_16x16x32_bf16(a, b, acc[c], 0, 0, 0);
            }
        }
        __syncthreads();
    }
#pragma unroll
    for (int c = 0; c < 16; ++c) {
        int col = c * 16 + l16;
        float bcol = (!SLICEOUT) ? bias[col] : 0.0f;
#pragma unroll
        for (int r = 0; r < 4; ++r) {
            int row = row0 + w * 16 + quad * 4 + r;
            if (row < M) {
                if (SLICEOUT)
                    Cout[((size_t)(c >> 1) * M + row) * 32 + ((c & 1) << 4) + l16] = f2b(acc[c][r]);
                else
                    Cout[(size_t)row * 256 + col] = f2b(acc[c][r] + bcol);
            }
        }
    }
}

// ---------------- aggregation: 4-lane group per slot, slice-major table, LDS edges ------
// Slots degree-sorted (descending): 16 groups per wave see near-equal row lengths.
// slice = blockIdx & mask -> XCD-resident 3.2MB slice. 16 KB LDS edge stage.

#define CAPQ 1024   // 4096 edges, 16 KB LDS

template <int CSH>
__global__ __launch_bounds__(256) void agg_grp(
    const unsigned short* __restrict__ tab0, const int* __restrict__ row_ptr,
    const unsigned int* __restrict__ edge, unsigned short* __restrict__ outb, int n) {
    __shared__ uint4v eq[CAPQ];
    int b = blockIdx.x;
    int s = b & ((1 << CSH) - 1);
    int grp = b >> CSH;
    int t = threadIdx.x;
    int d0 = grp * 64;
    int d = d0 + (t >> 2);

    const uint4v* e4p = (const uint4v*)edge;
    int qbase = row_ptr[d0] >> 2;
    int dmax = d0 + 64 < n ? d0 + 64 : n;
    int qcnt = (row_ptr[dmax] >> 2) - qbase;
    int qstage = qcnt < CAPQ ? qcnt : CAPQ;
    for (int i = t; i < qstage; i += 256) eq[i] = NT_LOAD(&e4p[qbase + i]);
    __syncthreads();

    if (d >= n) return;
    int fo = (t & 3) << 3;                    // feature offset within the 32-wide slice
    const unsigned short* tab = tab0 + (size_t)s * n * 32;

    int j = row_ptr[d] >> 2, j1 = row_ptr[d + 1] >> 2;
    int jmid = j1 < qbase + CAPQ ? j1 : qbase + CAPQ;

    float2v a2[4];
#pragma unroll
    for (int k = 0; k < 4; ++k) a2[k] = (float2v){0.f, 0.f};

    auto process = [&](uint4v e4) {
#pragma unroll
        for (int u = 0; u < 4; ++u) {
            unsigned e = e4[u];
            float wq = __int_as_float((int)(e & 0xffff0000u));
            float2v w2 = {wq, wq};
            unsigned off = ((e & 0xffffu) << 5) + (unsigned)fo;
            uint4 rr = *(const uint4*)(tab + off);
            unsigned uu0 = rr.x, uu1 = rr.y, uu2 = rr.z, uu3 = rr.w;
            float2v f0 = {__uint_as_float(uu0 << 16), __uint_as_float(uu0 & 0xffff0000u)};
            float2v f1 = {__uint_as_float(uu1 << 16), __uint_as_float(uu1 & 0xffff0000u)};
            float2v f2 = {__uint_as_float(uu2 << 16), __uint_as_float(uu2 & 0xffff0000u)};
            float2v f3 = {__uint_as_float(uu3 << 16), __uint_as_float(uu3 & 0xffff0000u)};
            a2[0] += f0 * w2;
            a2[1] += f1 * w2;
            a2[2] += f2 * w2;
            a2[3] += f3 * w2;
        }
    };

    for (; j + 2 <= jmid; j += 2) {
        uint4v e4a = eq[j - qbase];
        uint4v e4b = eq[j + 1 - qbase];
        process(e4a);
        process(e4b);
    }
    if (j < jmid) { process(eq[j - qbase]); ++j; }
    for (; j < j1; ++j) process(NT_LOAD(&e4p[j]));   // overflow fallback (first blocks only)

    ushort8 o;
#pragma unroll
    for (int k = 0; k < 4; ++k) {
        o[2 * k] = f2b(a2[k].x);
        o[2 * k + 1] = f2b(a2[k].y);
    }
    *(ushort8*)(outb + ((size_t)d << (5 + CSH)) + (s << 5) + fo) = o;
}

// ---------------- bias + LayerNorm + residual + ReLU (bf16 in, bf16 out) ----------------

__global__ __launch_bounds__(256) void ln_res_relu(
    const unsigned short* __restrict__ preln, const float* __restrict__ bias,
    const float* __restrict__ g, const float* __restrict__ lb,
    const unsigned short* __restrict__ res, unsigned short* __restrict__ out, int n) {
    int wv = __builtin_amdgcn_readfirstlane(threadIdx.x >> 6);
    int d = blockIdx.x * 4 + wv;
    if (d >= n) return;
    int l = threadIdx.x & 63;
    int fo = l * 4;
    ushort4 pv = *(const ushort4*)&preln[(size_t)d * 256 + fo];
    float4 bb = *(const float4*)&bias[fo];
    float v[4] = {b2f(pv.x) + bb.x, b2f(pv.y) + bb.y, b2f(pv.z) + bb.z, b2f(pv.w) + bb.w};
    float s4 = v[0] + v[1] + v[2] + v[3];
#pragma unroll
    for (int off = 1; off < 64; off <<= 1) s4 += __shfl_xor(s4, off);
    float mu = s4 * (1.0f / 256.0f);
    float dv[4];
    float qs = 0.f;
#pragma unroll
    for (int j = 0; j < 4; ++j) { dv[j] = v[j] - mu; qs += dv[j] * dv[j]; }
#pragma unroll
    for (int off = 1; off < 64; off <<= 1) qs += __shfl_xor(qs, off);
    float rs = rsqrtf(qs * (1.0f / 256.0f) + EPS);

    float4 gg = *(const float4*)&g[fo];
    float4 lbv = *(const float4*)&lb[fo];
    ushort4 rr4 = *(const ushort4*)&res[(size_t)d * 256 + fo];
    float ggv[4] = {gg.x, gg.y, gg.z, gg.w};
    float lbvv[4] = {lbv.x, lbv.y, lbv.z, lbv.w};
    float rrv[4] = {b2f(rr4.x), b2f(rr4.y), b2f(rr4.z), b2f(rr4.w)};
    ushort4 o;
    unsigned short* op = (unsigned short*)&o;
#pragma unroll
    for (int j = 0; j < 4; ++j) {
        float x = dv[j] * rs * ggv[j] + lbvv[j] + rrv[j];
        op[j] = f2b(x > 0.f ? x : 0.f);
    }
    *(ushort4*)&out[(size_t)d * 256 + fo] = o;
}

// ---------------- head ----------------

__global__ __launch_bounds__(256) void colsum_kernel(const unsigned short* __restrict__ x,
                                                     float* __restrict__ sums, int n) {
    int h = threadIdx.x;
    float acc = 0.0f;
    for (int r = blockIdx.x; r < n; r += gridDim.x) acc += b2f(x[(size_t)r * 256 + h]);
    atomicAdd(&sums[h], acc);
}

__global__ __launch_bounds__(64) void final_kernel(const float* __restrict__ sums,
                                                   const float* __restrict__ fcW,
                                                   const float* __restrict__ fcb,
                                                   float* __restrict__ out, float invN) {
    int lane = threadIdx.x;
    float p0 = 0.0f, p1 = 0.0f;
    for (int hh = lane; hh < 256; hh += 64) {
        float m = sums[hh];
        p0 += m * fcW[hh * 2 + 0];
        p1 += m * fcW[hh * 2 + 1];
    }
    for (int off = 32; off > 0; off >>= 1) {
        p0 += __shfl_down(p0, off);
        p1 += __shfl_down(p1, off);
    }
    if (lane == 0) {
        out[0] = p0 * invN + fcb[0];
        out[1] = p1 * invN + fcb[1];
    }
}

// ---------------- launch ----------------

extern "C" void kernel_launch(void* const* d_in, const int* in_sizes, int n_in,
                              void* d_out, int out_size, void* d_ws, size_t ws_size,
                              hipStream_t stream) {
    const float* node    = (const float*)d_in[0];
    const int*   edges   = (const int*)d_in[1];
    const float* eattr   = (const float*)d_in[2];
    const float* W1      = (const float*)d_in[3];
    const float* b1      = (const float*)d_in[4];
    const float* W_convs = (const float*)d_in[5];
    const float* b_convs = (const float*)d_in[6];
    const float* ln_g    = (const float*)d_in[7];
    const float* ln_b    = (const float*)d_in[8];
    const float* fc_W    = (const float*)d_in[9];
    const float* fc_b    = (const float*)d_in[10];
    float* out = (float*)d_out;

    const int H = in_sizes[4];           // 256
    const int F = in_sizes[3] / H;       // 128
    const int N = in_sizes[0] / F;       // 50000
    const int E = in_sizes[2];           // 1600000
    const int L = in_sizes[6] / H;       // 3

    const int* src = edges;
    const int* dst = edges + E;

    char* p = (char*)d_ws;
    auto alloc = [&](size_t bytes) {
        char* r = p;
        p += (bytes + 255) & ~(size_t)255;
        return r;
    };
    int nblk = (N + 255) / 256;
    // zeroed region: padded combo (64B/node) + colsums, contiguous
    unsigned long long* combo = (unsigned long long*)alloc((size_t)N * 64);
    float* colsums = (float*)alloc((size_t)H * 4);
    size_t zero_bytes = (size_t)((char*)colsums - (char*)combo) + (((size_t)H * 4 + 255) & ~(size_t)255);
    int*   blockhist = (int*)alloc((size_t)nblk * NBK * 4);
    int*   blockpre  = (int*)alloc((size_t)nblk * NBK * 4);
    int*   tot       = (int*)alloc((size_t)NBK * 4);
    int*   bbase     = (int*)alloc((size_t)NBK * 4);
    int*   perm    = (int*)alloc((size_t)N * 4);
    int*   posod   = (int*)alloc((size_t)N * 4);
    int*   qlen    = (int*)alloc((size_t)N * 4);
    float* dinv    = (float*)alloc((size_t)N * 4);
    int*   row_ptr = (int*)alloc((size_t)(N + 1) * 4);
    unsigned int* edge = (unsigned int*)alloc(((size_t)E + 4 * (size_t)N + 64) * 4);
    unsigned short* Wt1 = (unsigned short*)alloc((size_t)H * F * 2);
    unsigned short* Wtc = (unsigned short*)alloc((size_t)L * H * H * 2);
    unsigned short* xw  = (unsigned short*)alloc((size_t)N * H * 2);   // sliced [8][N][32]
    unsigned short* preln = (unsigned short*)alloc((size_t)N * H * 2); // row-major [N][256]
    unsigned short* bufA  = (unsigned short*)alloc((size_t)N * H * 2); // bf16 x
    unsigned short* bufB  = (unsigned short*)alloc((size_t)N * H * 2); // bf16 x
    // aliases (dead before their slabs' first real use):
    int*            rank  = (int*)xw;                     // E*4 <= N*H*2
    unsigned short* nodeb = preln;                        // sliced [4][N][32] = N*128 shorts
    unsigned short* aggn  = preln + (size_t)N * F;        // bf16 [N][128] row-major

    hipMemsetAsync(combo, 0, zero_bytes, stream);

    int gE = (E + 255) / 256;
    rank_kernel<<<gE, 256, 0, stream>>>(dst, eattr, combo, rank, E);
    dinv_kernel<<<nblk, 256, 0, stream>>>(combo, dinv, N);
    bin_hist_kernel<<<nblk, 256, 0, stream>>>(combo, blockhist, N);
    bin_prescan_kernel<<<NBK, 256, 0, stream>>>(blockhist, blockpre, tot, nblk);
    bin_suffix_kernel<<<1, 64, 0, stream>>>(tot, bbase);
    bin_scatter_kernel<<<nblk, 256, 0, stream>>>(combo, bbase, blockpre, perm, posod, qlen, N);
    scan_kernel<<<1, 1024, 0, stream>>>(qlen, row_ptr, N);
    selfpad_kernel<<<nblk, 256, 0, stream>>>(combo, row_ptr, posod, dinv, edge, N);
    scatter2_kernel<<<gE, 256, 0, stream>>>(src, dst, eattr, rank, row_ptr, posod, dinv, edge, E);

    cast_sliced_kernel<<<(N * (F / 4) + 255) / 256, 256, 0, stream>>>(node, perm, nodeb, N, F);
    wtrans_kernel<<<(F * H + 255) / 256, 256, 0, stream>>>(W1, Wt1, F, H);
    for (int i = 0; i < L; ++i)
        wtrans_kernel<<<(H * H + 255) / 256, 256, 0, stream>>>(
            W_convs + (size_t)i * H * H, Wtc + (size_t)i * H * H, H, H);

    int ngrp64 = (N + 63) / 64;
    int lngrid = (N + 3) / 4;
    int ggrid = (N + 63) / 64;

    // layer 1 (slot space): aggn = agg(node); x1 = aggn @ W1 + b1 (bf16)
    agg_grp<2><<<4 * ngrp64, 256, 0, stream>>>(nodeb, row_ptr, edge, aggn, N);
    gemm_n256<false><<<ggrid, 256, 0, stream>>>(aggn, Wt1, bufA, b1, N, F);

    unsigned short* x = bufA;
    unsigned short* other = bufB;
    for (int i = 0; i < L; ++i) {
        gemm_n256<true><<<ggrid, 256, 0, stream>>>(x, Wtc + (size_t)i * H * H, xw, nullptr, N, H);
        agg_grp<3><<<8 * ngrp64, 256, 0, stream>>>(xw, row_ptr, edge, preln, N);
        ln_res_relu<<<lngrid, 256, 0, stream>>>(preln, b_convs + (size_t)i * H,
                                                ln_g + (size_t)i * H, ln_b + (size_t)i * H,
                                                x, other, N);
        unsigned short* t = x; x = other; other = t;
    }

    colsum_kernel<<<256, 256, 0, stream>>>(x, colsums, N);
    final_kernel<<<1, 64, 0, stream>>>(colsums, fc_W, fc_b, out, 1.0f / (float)N);
}